// Round 6
// baseline (724.814 us; speedup 1.0000x reference)
//
#include <hip/hip_runtime.h>
#include <math.h>

typedef _Float16 half_t;
typedef __attribute__((ext_vector_type(8))) _Float16 f16x8;
typedef __attribute__((ext_vector_type(4))) _Float16 f16x4;
typedef __attribute__((ext_vector_type(4))) float f32x4;

#define LEAKY(v, s) ((v) >= 0.f ? (v) : (s) * (v))

__device__ __forceinline__ float sig_(float x) { return 1.f / (1.f + expf(-x)); }
__device__ __forceinline__ half_t f2h(float f) { return (half_t)f; }

#define GLD(gp, lp)                                              \
  __builtin_amdgcn_global_load_lds(                              \
      (const __attribute__((address_space(1))) void*)(gp),       \
      (__attribute__((address_space(3))) void*)(lp), 16, 0, 0)

#define PHASE_WAIT(N)                                            \
  asm volatile("s_waitcnt vmcnt(" #N ")" ::: "memory");          \
  __builtin_amdgcn_s_barrier();                                  \
  __builtin_amdgcn_sched_barrier(0)

// ---------------- utility / prep kernels ----------------
__global__ void add_pair_f32(const float* __restrict__ a, const float* __restrict__ b,
                             float* __restrict__ out, int n) {
  int i = blockIdx.x * blockDim.x + threadIdx.x;
  if (i < n) out[i] = a[i] + b[i];
}

__global__ void zero_f32(float* p, int n) {
  int i = blockIdx.x * blockDim.x + threadIdx.x;
  if (i < n) p[i] = 0.f;
}

__global__ void cast_f16(const float* __restrict__ in, half_t* __restrict__ out, int n) {
  int i = blockIdx.x * blockDim.x + threadIdx.x;
  if (i < n) out[i] = f2h(in[i]);
}

// x [128,3,64,64] f32 -> xpad [128,70,70,8] fp16
__global__ void pad_x_kernel(const float* __restrict__ x, half_t* __restrict__ xp) {
  int i = blockIdx.x * blockDim.x + threadIdx.x;
  if (i >= 128 * 70 * 70 * 8) return;
  int c = i & 7;
  int t = i >> 3;
  int iw = t % 70; t /= 70;
  int ih = t % 70;
  int n = t / 70;
  float v = 0.f;
  if (c < 3 && ih >= 3 && ih < 67 && iw >= 3 && iw < 67)
    v = x[((n * 3 + c) * 64 + (ih - 3)) * 64 + (iw - 3)];
  xp[i] = f2h(v);
}

__global__ void reorder_w1_kernel(const float* __restrict__ w, half_t* __restrict__ wr) {
  int i = blockIdx.x * blockDim.x + threadIdx.x;
  if (i >= 64 * 416) return;
  int kg = i % 416;
  int co = i / 416;
  int ci = kg & 7;
  int tap = kg >> 3;
  float v = 0.f;
  if (tap < 49 && ci < 3) {
    int kh = tap / 7, kw = tap % 7;
    v = w[((co * 3 + ci) * 7 + kh) * 7 + kw];
  }
  wr[i] = f2h(v);
}

__global__ void reorder_w_kernel(const float* __restrict__ w, half_t* __restrict__ wr,
                                 int total, int K, int KW, int KH, int log2Cin) {
  int i = blockIdx.x * blockDim.x + threadIdx.x;
  if (i >= total) return;
  int kg = i % K;
  int co = i / K;
  int Cin = 1 << log2Cin;
  int ci = kg & (Cin - 1);
  int tap = kg >> log2Cin;
  int kh = tap / KW, kw = tap - kh * KW;
  wr[i] = f2h(w[(((size_t)co * Cin + ci) * KH + kh) * KW + kw]);
}

__global__ void build_wcat0(const float* __restrict__ whh, half_t* __restrict__ out) {
  int i = blockIdx.x * blockDim.x + threadIdx.x;
  if (i >= 2048 * 512) return;
  int r = i >> 9, k = i & 511;
  int u = r >> 2, g = r & 3;
  out[i] = f2h(whh[(g * 512 + u) * 512 + k]);
}

__global__ void build_wcat1(const float* __restrict__ wih, const float* __restrict__ whh,
                            half_t* __restrict__ out) {
  int i = blockIdx.x * blockDim.x + threadIdx.x;
  if (i >= 2048 * 1024) return;
  int r = i >> 10, k = i & 1023;
  int u = r >> 2, g = r & 3;
  int row = g * 512 + u;
  out[i] = f2h(k < 512 ? wih[row * 512 + k] : whh[row * 512 + (k - 512)]);
}

// ---------------- 64x64 fp16 MFMA conv / GEMM (proven, round 5) ----------------
template <int KW, int S, int LOG2CIN, int OUTMODE>
__global__ __launch_bounds__(256) void conv_mfma(
    const half_t* __restrict__ xin, const half_t* __restrict__ wr,
    const float* __restrict__ bias, void* __restrict__ outp,
    int Hin, int Win, int Hout, int Wout, int Cout, int K, int ktiles, float slope,
    long long zstride) {
  constexpr int CIN = 1 << LOG2CIN;
  __shared__ half_t lds[4][4096];
  const int tid = threadIdx.x;
  const int lane = tid & 63, wid = tid >> 6;
  const int sRow = tid >> 2, sCh = tid & 3;
  const int sSwz = sCh ^ ((sRow ^ (sRow >> 2)) & 3);
  const int kt0 = blockIdx.z * ktiles;
  const half_t* gArow = wr + (size_t)(blockIdx.y * 64 + sRow) * K + sSwz * 8;
  int p = blockIdx.x * 64 + sRow;
  int hw = Hout * Wout;
  int n = p / hw;
  int rem = p - n * hw;
  int oh = rem / Wout;
  int ow = rem - oh * Wout;
  const half_t* xb = xin + ((size_t)(n * Hin + oh * S) * Win + ow * S) * CIN;
  const int fr = lane & 15, fc = lane >> 4;
  const int r0 = (wid & 1) * 32, c0 = (wid >> 1) * 32;
  const int sw = (fc ^ ((fr ^ (fr >> 2)) & 3)) * 8;
  const int ia0 = (r0 + fr) * 32 + sw;
  const int ia1 = (r0 + 16 + fr) * 32 + sw;
  const int ib0 = 2048 + (c0 + fr) * 32 + sw;
  const int ib1 = 2048 + (c0 + 16 + fr) * 32 + sw;

  auto stage = [&](int t, int buf) {
    GLD(gArow + (size_t)(kt0 + t) * 32, &lds[buf][wid * 512]);
    int kg = (kt0 + t) * 32 + sSwz * 8;
    int ci = kg & (CIN - 1);
    int tap = kg >> LOG2CIN;
    int kh = tap / KW, kw = tap - kh * KW;
    GLD(xb + (kh * Win + kw) * CIN + ci, &lds[buf][2048 + wid * 512]);
  };

  f32x4 acc00 = {0.f, 0.f, 0.f, 0.f};
  f32x4 acc01 = acc00, acc10 = acc00, acc11 = acc00;

  auto compute = [&](int buf) {
    const half_t* L = &lds[buf][0];
    f16x8 a0 = *(const f16x8*)&L[ia0];
    f16x8 a1 = *(const f16x8*)&L[ia1];
    f16x8 b0 = *(const f16x8*)&L[ib0];
    f16x8 b1 = *(const f16x8*)&L[ib1];
    acc00 = __builtin_amdgcn_mfma_f32_16x16x32_f16(a0, b0, acc00, 0, 0, 0);
    acc01 = __builtin_amdgcn_mfma_f32_16x16x32_f16(a0, b1, acc01, 0, 0, 0);
    acc10 = __builtin_amdgcn_mfma_f32_16x16x32_f16(a1, b0, acc10, 0, 0, 0);
    acc11 = __builtin_amdgcn_mfma_f32_16x16x32_f16(a1, b1, acc11, 0, 0, 0);
  };

  stage(0, 0);
  stage(1, 1);
  stage(2, 2);
  int t = 0;
  for (; t < ktiles - 3; ++t) {
    PHASE_WAIT(4);
    stage(t + 3, (t + 3) & 3);
    compute(t & 3);
  }
  PHASE_WAIT(4);
  compute(t & 3);
  ++t;
  PHASE_WAIT(2);
  compute(t & 3);
  ++t;
  PHASE_WAIT(0);
  compute(t & 3);

#pragma unroll
  for (int am = 0; am < 2; ++am) {
#pragma unroll
    for (int bn = 0; bn < 2; ++bn) {
      f32x4 a = am == 0 ? (bn == 0 ? acc00 : acc01) : (bn == 0 ? acc10 : acc11);
      int co = blockIdx.y * 64 + r0 + am * 16 + fc * 4;
      int px = blockIdx.x * 64 + c0 + bn * 16 + fr;
      size_t o = (size_t)px * Cout + co;
      if (OUTMODE == 2) {
        float* pb = (float*)outp + (size_t)blockIdx.z * zstride;
        *(f32x4*)&pb[o] = a;
      } else {
        f32x4 bb = *(const f32x4*)&bias[co];
        f32x4 v;
#pragma unroll
        for (int j = 0; j < 4; ++j) {
          float tt = a[j] + bb[j];
          v[j] = LEAKY(tt, slope);
        }
        if (OUTMODE == 1) {
          *(f32x4*)&((float*)outp)[o] = v;
        } else {
          f16x4 hv;
#pragma unroll
          for (int j = 0; j < 4; ++j) hv[j] = f2h(v[j]);
          *(f16x4*)&((half_t*)outp)[o] = hv;
        }
      }
    }
  }
}

// ---------------- 128x128 fp16 MFMA conv (4 waves, 4x4 frags/wave) ----------------
// OUTMODE: 0 fp16+bias+leaky; 2 f32 raw partial at z*zstride.
template <int KW, int S, int LOG2CIN, int OUTMODE>
__global__ __launch_bounds__(256) void conv_mfma128(
    const half_t* __restrict__ xin, const half_t* __restrict__ wr,
    const float* __restrict__ bias, void* __restrict__ outp,
    int Hin, int Win, int Hout, int Wout, int Cout, int K, int ktiles, float slope,
    long long zstride) {
  constexpr int CIN = 1 << LOG2CIN;
  __shared__ half_t lds[4][8192];  // per buf: A[128][32] at 0, B[128][32] at 4096
  const int tid = threadIdx.x;
  const int lane = tid & 63, wid = tid >> 6;
  const int sRow = tid >> 2, sCh = tid & 3;
  const int sSwz = sCh ^ ((sRow ^ (sRow >> 2)) & 3);
  const int kt0 = blockIdx.z * ktiles;
  const half_t* gA0 = wr + (size_t)(blockIdx.y * 128 + sRow) * K + sSwz * 8;
  const half_t* gA1 = wr + (size_t)(blockIdx.y * 128 + 64 + sRow) * K + sSwz * 8;
  int hw = Hout * Wout;
  int p0 = blockIdx.x * 128 + sRow;
  int n0 = p0 / hw, r0p = p0 - n0 * hw, oh0 = r0p / Wout, ow0 = r0p - oh0 * Wout;
  const half_t* xb0 = xin + ((size_t)(n0 * Hin + oh0 * S) * Win + ow0 * S) * CIN;
  int p1 = p0 + 64;
  int n1 = p1 / hw, r1p = p1 - n1 * hw, oh1 = r1p / Wout, ow1 = r1p - oh1 * Wout;
  const half_t* xb1 = xin + ((size_t)(n1 * Hin + oh1 * S) * Win + ow1 * S) * CIN;

  const int fr = lane & 15, fc = lane >> 4;
  const int wr_ = wid & 1, wc_ = wid >> 1;
  const int sw = (fc ^ ((fr ^ (fr >> 2)) & 3)) * 8;
  const int iaB = (wr_ * 64 + fr) * 32 + sw;
  const int ibB = 4096 + (wc_ * 64 + fr) * 32 + sw;

  auto stage = [&](int t, int buf) {
    half_t* LB = &lds[buf][0];
    GLD(gA0 + (size_t)(kt0 + t) * 32, LB + wid * 512);
    GLD(gA1 + (size_t)(kt0 + t) * 32, LB + 2048 + wid * 512);
    int kg = (kt0 + t) * 32 + sSwz * 8;
    int ci = kg & (CIN - 1);
    int tap = kg >> LOG2CIN;
    int kh = tap / KW, kw = tap - kh * KW;
    int xoff = (kh * Win + kw) * CIN + ci;
    GLD(xb0 + xoff, LB + 4096 + wid * 512);
    GLD(xb1 + xoff, LB + 6144 + wid * 512);
  };

  f32x4 acc[4][4];
#pragma unroll
  for (int i = 0; i < 4; ++i)
#pragma unroll
    for (int j = 0; j < 4; ++j) acc[i][j] = (f32x4){0.f, 0.f, 0.f, 0.f};

  auto compute = [&](int buf) {
    const half_t* L = &lds[buf][0];
    f16x8 a[4], b[4];
#pragma unroll
    for (int fi = 0; fi < 4; ++fi) a[fi] = *(const f16x8*)&L[iaB + fi * 512];
#pragma unroll
    for (int fj = 0; fj < 4; ++fj) b[fj] = *(const f16x8*)&L[ibB + fj * 512];
#pragma unroll
    for (int fi = 0; fi < 4; ++fi)
#pragma unroll
      for (int fj = 0; fj < 4; ++fj)
        acc[fi][fj] = __builtin_amdgcn_mfma_f32_16x16x32_f16(a[fi], b[fj], acc[fi][fj], 0, 0, 0);
  };

  stage(0, 0);
  stage(1, 1);
  stage(2, 2);
  int t = 0;
  for (; t < ktiles - 3; ++t) {
    PHASE_WAIT(8);
    stage(t + 3, (t + 3) & 3);
    compute(t & 3);
  }
  PHASE_WAIT(8);
  compute(t & 3);
  ++t;
  PHASE_WAIT(4);
  compute(t & 3);
  ++t;
  PHASE_WAIT(0);
  compute(t & 3);

#pragma unroll
  for (int fi = 0; fi < 4; ++fi) {
#pragma unroll
    for (int fj = 0; fj < 4; ++fj) {
      int co = blockIdx.y * 128 + wr_ * 64 + fi * 16 + fc * 4;
      int px = blockIdx.x * 128 + wc_ * 64 + fj * 16 + fr;
      size_t o = (size_t)px * Cout + co;
      if (OUTMODE == 2) {
        float* pb = (float*)outp + (size_t)blockIdx.z * zstride;
        *(f32x4*)&pb[o] = acc[fi][fj];
      } else {
        f32x4 bb = *(const f32x4*)&bias[co];
        f16x4 hv;
#pragma unroll
        for (int j = 0; j < 4; ++j) {
          float tt = acc[fi][fj][j] + bb[j];
          hv[j] = f2h(LEAKY(tt, slope));
        }
        *(f16x4*)&((half_t*)outp)[o] = hv;
      }
    }
  }
}

// reduce K-split f32 partials: out[i] = f2h(leaky(sum_z pb[z][i] + bias[i&511], 0.2))
__global__ void finalize_part(const float* __restrict__ pb, const float* __restrict__ bias,
                              half_t* __restrict__ out, int size, int nz) {
  int i = blockIdx.x * blockDim.x + threadIdx.x;
  if (i >= size) return;
  float s = bias[i & 511];
  for (int z = 0; z < nz; ++z) s += pb[(size_t)z * size + i];
  out[i] = f2h(LEAKY(s, 0.2f));
}

// ---------------- persistent 2-layer LSTM ----------------
// 128 blocks x 128 threads (2 waves), 1 block/CU (128KB LDS). blocks 0-63: layer0
// (K=512), 64-127: layer1 (K=1024). Weights resident in LDS; c-state, xw0/bias in
// registers; h ping-pong via global, published by a hand-rolled grid barrier.
// 21 rounds: round r: l0 computes step r+1 (r<20), l1 computes step r (r>=1).
__device__ __forceinline__ void grid_barrier(unsigned* bar, unsigned target) {
  __syncthreads();
  if (threadIdx.x == 0) {
    __threadfence();
    __hip_atomic_fetch_add(bar, 1u, __ATOMIC_RELEASE, __HIP_MEMORY_SCOPE_AGENT);
    while (__hip_atomic_load(bar, __ATOMIC_ACQUIRE, __HIP_MEMORY_SCOPE_AGENT) < target)
      __builtin_amdgcn_s_sleep(8);
    __threadfence();
  }
  __syncthreads();
}

#define LSTM_GEMM(KTV, HA, HB)                                                    \
  {                                                                               \
    _Pragma("unroll") for (int kt = 0; kt < (KTV); ++kt) {                        \
      const half_t* hs_ = ((KTV) == 16 && kt >= 8) ? (HB) : (HA);                 \
      const int kof_ = ((KTV) == 16 && kt >= 8) ? (kt - 8) * 64 : kt * 64;        \
      f16x8 bv[2][2];                                                             \
      _Pragma("unroll") for (int s = 0; s < 2; ++s)                               \
        _Pragma("unroll") for (int fj = 0; fj < 2; ++fj)                          \
          bv[s][fj] = *(const f16x8*)&hs_[(size_t)(bcolb + fj * 16) * 512 +       \
                                          kof_ + s * 32 + fc * 8];                \
      _Pragma("unroll") for (int s = 0; s < 2; ++s) {                             \
        _Pragma("unroll") for (int fi = 0; fi < 4; ++fi) {                        \
          int row_ = fi * 16 + fr;                                                \
          f16x8 av = *(const f16x8*)&W[kt * 4096 + row_ * 64 +                    \
                                       (((s * 4 + fc) ^ (fr & 7)) * 8)];          \
          acc[fi][0] = __builtin_amdgcn_mfma_f32_16x16x32_f16(av, bv[s][0],       \
                                                              acc[fi][0], 0, 0, 0); \
          acc[fi][1] = __builtin_amdgcn_mfma_f32_16x16x32_f16(av, bv[s][1],       \
                                                              acc[fi][1], 0, 0, 0); \
        }                                                                         \
      }                                                                           \
    }                                                                             \
  }

#define LSTM_EPI(WRYS, HOUT, YSP)                                                 \
  {                                                                               \
    _Pragma("unroll") for (int fi = 0; fi < 4; ++fi) {                            \
      _Pragma("unroll") for (int fj = 0; fj < 2; ++fj) {                          \
        float ig = sig_(acc[fi][fj][0] + base[fi][fj][0]);                        \
        float fg = sig_(acc[fi][fj][1] + base[fi][fj][1]);                        \
        float gg = tanhf(acc[fi][fj][2] + base[fi][fj][2]);                       \
        float og = sig_(acc[fi][fj][3] + base[fi][fj][3]);                        \
        float cn = fg * creg[fi][fj] + ig * gg;                                   \
        float hn = og * tanhf(cn);                                                \
        creg[fi][fj] = cn;                                                        \
        int bc = bcolb + fj * 16;                                                 \
        int u = y * 16 + fi * 4 + fc;                                             \
        (HOUT)[(size_t)bc * 512 + u] = f2h(hn);                                   \
        if (WRYS) (YSP)[(size_t)bc * 512 + u] = f2h(hn);                          \
        acc[fi][fj] = (f32x4){0.f, 0.f, 0.f, 0.f};                                \
      }                                                                           \
    }                                                                             \
  }

__global__ __launch_bounds__(128, 1) void lstm_persist(
    const half_t* __restrict__ wcat0, const half_t* __restrict__ wcat1,
    const float* __restrict__ xw0, const float* __restrict__ bg1,
    half_t* h0a, half_t* h0b, half_t* h1a, half_t* h1b,
    half_t* ys, unsigned* bar) {
  __shared__ half_t W[65536];  // 128KB -> 1 block/CU
  const int tid = threadIdx.x;
  const int bid = blockIdx.x;
  const bool isL1 = bid >= 64;
  const int rid = isL1 ? bid - 64 : bid;
  const int y = rid >> 1, xh = rid & 1;
  const int KT = isL1 ? 16 : 8;
  const int K = KT * 64;
  const half_t* wsrc = (isL1 ? wcat1 : wcat0) + (size_t)(y * 64) * K;

  // load weight panel into LDS (chunk-XOR swizzle: slot = ch ^ (row&7))
  int nch = KT * 64 * 8;
  for (int idx = tid; idx < nch; idx += 128) {
    int ch = idx & 7, row = (idx >> 3) & 63, kt = idx >> 9;
    f16x8 v = *(const f16x8*)&wsrc[(size_t)row * K + kt * 64 + ch * 8];
    *(f16x8*)&W[kt * 4096 + row * 64 + (ch ^ (row & 7)) * 8] = v;
  }
  __syncthreads();

  const int lane = tid & 63, wid = tid >> 6;
  const int fr = lane & 15, fc = lane >> 4;
  const int bcolb = xh * 64 + wid * 32 + fr;  // batch base (fj adds 16)

  float base[4][2][4];
#pragma unroll
  for (int fi = 0; fi < 4; ++fi)
#pragma unroll
    for (int fj = 0; fj < 2; ++fj)
#pragma unroll
      for (int j = 0; j < 4; ++j) {
        int u = y * 16 + fi * 4 + fc;
        base[fi][fj][j] = isL1 ? bg1[j * 512 + u]
                               : xw0[(size_t)(bcolb + fj * 16) * 2048 + j * 512 + u];
      }
  float creg[4][2] = {{0.f, 0.f}, {0.f, 0.f}, {0.f, 0.f}, {0.f, 0.f}};
  f32x4 acc[4][2];
#pragma unroll
  for (int fi = 0; fi < 4; ++fi)
#pragma unroll
    for (int fj = 0; fj < 2; ++fj) acc[fi][fj] = (f32x4){0.f, 0.f, 0.f, 0.f};

  for (int r = 0; r < 21; ++r) {
    if (isL1) {
      if (r >= 1) {
        const half_t* h0cur = (r & 1) ? h0b : h0a;
        const half_t* h1prev = ((r - 1) & 1) ? h1b : h1a;
        LSTM_GEMM(16, h0cur, h1prev);
        half_t* hout = (r & 1) ? h1b : h1a;
        half_t* yso = ys + (size_t)(r - 1) * 65536;
        LSTM_EPI(true, hout, yso);
      }
    } else {
      if (r < 20) {
        const half_t* h0cur = (r & 1) ? h0b : h0a;
        LSTM_GEMM(8, h0cur, h0cur);
        half_t* hout = (r & 1) ? h0a : h0b;  // (r+1)&1
        LSTM_EPI(false, hout, hout);
      }
    }
    grid_barrier(bar, 128u * (r + 1));
  }
}

// ---------------- final FC: sigmoid(fc1o @ fw2.T + fb2), [2560,13] ----------------
__global__ void fc2_sigmoid(const half_t* __restrict__ in, const float* __restrict__ w,
                            const float* __restrict__ b, float* __restrict__ out) {
  int idx = blockIdx.x * blockDim.x + threadIdx.x;
  if (idx >= 2560 * 13) return;
  int j = idx % 13, r = idx / 13;
  const half_t* ip = in + (size_t)r * 512;
  const float* wp = w + j * 512;
  float s = b[j];
  for (int k = 0; k < 512; k += 8) {
    f16x8 hv = *(const f16x8*)&ip[k];
#pragma unroll
    for (int q = 0; q < 8; ++q) s = fmaf((float)hv[q], wp[k + q], s);
  }
  out[idx] = sig_(s);
}

// ---------------- launch ----------------
extern "C" void kernel_launch(void* const* d_in, const int* in_sizes, int n_in,
                              void* d_out, int out_size, void* d_ws, size_t ws_size,
                              hipStream_t stream) {
  const float* x   = (const float*)d_in[0];
  const float* w1  = (const float*)d_in[1];  const float* b1 = (const float*)d_in[2];
  const float* w2  = (const float*)d_in[3];  const float* b2 = (const float*)d_in[4];
  const float* w3  = (const float*)d_in[5];  const float* b3 = (const float*)d_in[6];
  const float* w4  = (const float*)d_in[7];  const float* b4 = (const float*)d_in[8];
  const float* w5  = (const float*)d_in[9];  const float* b5 = (const float*)d_in[10];
  const float* wih0 = (const float*)d_in[11]; const float* whh0 = (const float*)d_in[12];
  const float* bih0 = (const float*)d_in[13]; const float* bhh0 = (const float*)d_in[14];
  const float* wih1 = (const float*)d_in[15]; const float* whh1 = (const float*)d_in[16];
  const float* bih1 = (const float*)d_in[17]; const float* bhh1 = (const float*)d_in[18];
  const float* fw1 = (const float*)d_in[19]; const float* fb1 = (const float*)d_in[20];
  const float* fw2 = (const float*)d_in[21]; const float* fb2 = (const float*)d_in[22];
  float* out = (float*)d_out;

  // ---- workspace layout (~68.1 MB total; 75 MB proven safe) ----
  unsigned* bar = (unsigned*)d_ws;          // 16 f32 slots
  float* bg0 = (float*)d_ws + 16;           // 2048
  float* bg1 = bg0 + 2048;                  // 2048
  float* xw0 = bg1 + 2048;                  // 262144
  half_t* h0a = (half_t*)(xw0 + 262144);    // 4 x 65536 halves
  half_t* h0b = h0a + 65536;
  half_t* h1a = h0b + 65536;
  half_t* h1b = h1a + 65536;
  half_t* BUF1 = h1b + 65536;               // 8,388,608  [A1 -> A3 -> feat]
  half_t* BUF2 = BUF1 + 8388608;            // 2,768,896  [A2 -> A4 -> ys+fc1o]
  half_t* w1r  = BUF2 + 2768896;            // 26,624
  half_t* w2r  = w1r + 26624;               // 401,408
  half_t* w3r  = w2r + 401408;              // 819,200
  half_t* w4r  = w3r + 819200;              // 3,276,800
  half_t* w5r  = w4r + 3276800;             // 6,553,600
  half_t* wih0h  = w5r + 6553600;           // 1,048,576
  half_t* wcat0h = wih0h + 1048576;         // 1,048,576
  half_t* wcat1h = wcat0h + 1048576;        // 2,097,152
  half_t* fw1h   = wcat1h + 2097152;        // 262,144
  half_t* xpad   = fw1h + 262144;           // 5,017,600 (+slack; pb overlays)
  float* pbC = (float*)xpad;                // up to 3,276,800 f32 (conv4/conv5 partials)

  half_t* A1 = BUF1;                        // [131072 px][64]
  half_t* A2 = BUF2;                        // [21632][128]
  half_t* A3 = BUF1;                        // [10368][256]
  half_t* A4 = BUF2;                        // [3200][512]  (A2 dead)
  half_t* feat = BUF1;                      // [128][512]   (A3 dead)
  half_t* ys   = BUF2;                      // [2560][512]  (A4 dead post-conv5)
  half_t* fc1o = BUF2 + 1310720;

  dim3 blk(256);

  // ---- prep ----
  add_pair_f32<<<8, blk, 0, stream>>>(bih0, bhh0, bg0, 2048);
  add_pair_f32<<<8, blk, 0, stream>>>(bih1, bhh1, bg1, 2048);
  zero_f32<<<1, blk, 0, stream>>>((float*)bar, 16);
  zero_f32<<<512, blk, 0, stream>>>((float*)h0a, 131072);  // h0a..h1b
  pad_x_kernel<<<19600, blk, 0, stream>>>(x, xpad);
  reorder_w1_kernel<<<104, blk, 0, stream>>>(w1, w1r);
  reorder_w_kernel<<<1568, blk, 0, stream>>>(w2, w2r, 401408, 3136, 7, 7, 6);
  reorder_w_kernel<<<3200, blk, 0, stream>>>(w3, w3r, 819200, 3200, 5, 5, 7);
  reorder_w_kernel<<<12800, blk, 0, stream>>>(w4, w4r, 3276800, 6400, 5, 5, 8);
  reorder_w_kernel<<<25600, blk, 0, stream>>>(w5, w5r, 6553600, 12800, 5, 5, 9);
  cast_f16<<<4096, blk, 0, stream>>>(wih0, wih0h, 1048576);
  cast_f16<<<1024, blk, 0, stream>>>(fw1, fw1h, 262144);
  build_wcat0<<<4096, blk, 0, stream>>>(whh0, wcat0h);
  build_wcat1<<<8192, blk, 0, stream>>>(wih1, whh1, wcat1h);

  // ---- conv stack ----
  conv_mfma<7, 2, 3, 0><<<dim3(2048, 1, 1), blk, 0, stream>>>(
      xpad, w1r, b1, A1, 70, 70, 32, 32, 64, 416, 13, 0.2f, 0);
  conv_mfma128<7, 2, 6, 0><<<dim3(169, 1, 1), blk, 0, stream>>>(
      A1, w2r, b2, A2, 32, 32, 13, 13, 128, 3136, 98, 0.2f, 0);
  conv_mfma128<5, 1, 7, 0><<<dim3(81, 2, 1), blk, 0, stream>>>(
      A2, w3r, b3, A3, 13, 13, 9, 9, 256, 3200, 100, 0.2f, 0);
  // conv4: K-split x2 -> f32 partials in pbC, finalize -> A4 (BUF2)
  conv_mfma128<5, 1, 8, 2><<<dim3(25, 4, 2), blk, 0, stream>>>(
      A3, w4r, b4, pbC, 9, 9, 5, 5, 512, 6400, 100, 0.2f, (long long)3200 * 512);
  finalize_part<<<6400, blk, 0, stream>>>(pbC, b4, A4, 1638400, 2);
  // conv5: K-split x25 -> partials, finalize -> feat
  conv_mfma<5, 1, 9, 2><<<dim3(2, 8, 25), blk, 0, stream>>>(
      A4, w5r, b5, pbC, 5, 5, 1, 1, 512, 12800, 16, 0.2f, (long long)65536);
  finalize_part<<<256, blk, 0, stream>>>(pbC, b5, feat, 65536, 25);

  // xw0 = feat @ wih0.T + bg0   [128][2048] f32 (slope=1 -> identity)
  conv_mfma<1, 1, 9, 1><<<dim3(2, 32, 1), blk, 0, stream>>>(
      feat, wih0h, bg0, xw0, 1, 1, 1, 1, 2048, 512, 16, 1.0f, 0);

  // ---- 2-layer LSTM, 20 steps: one persistent kernel, 21 internal rounds ----
  lstm_persist<<<128, dim3(128), 0, stream>>>(
      wcat0h, wcat1h, xw0, bg1, h0a, h0b, h1a, h1b, ys, bar);

  // ---- FC head ----
  conv_mfma<1, 1, 9, 0><<<dim3(40, 8, 1), blk, 0, stream>>>(
      ys, fw1h, fb1, fc1o, 1, 1, 1, 1, 512, 512, 16, 0.01f, 0);
  fc2_sigmoid<<<130, blk, 0, stream>>>(fc1o, fw2, fb2, out);
}

// Round 7
// 501.719 us; speedup vs baseline: 1.4447x; 1.4447x over previous
//
#include <hip/hip_runtime.h>
#include <math.h>

typedef _Float16 half_t;
typedef __attribute__((ext_vector_type(8))) _Float16 f16x8;
typedef __attribute__((ext_vector_type(4))) _Float16 f16x4;
typedef __attribute__((ext_vector_type(4))) float f32x4;

#define LEAKY(v, s) ((v) >= 0.f ? (v) : (s) * (v))

__device__ __forceinline__ float sig_(float x) { return 1.f / (1.f + expf(-x)); }
__device__ __forceinline__ half_t f2h(float f) { return (half_t)f; }

#define GLD(gp, lp)                                              \
  __builtin_amdgcn_global_load_lds(                              \
      (const __attribute__((address_space(1))) void*)(gp),       \
      (__attribute__((address_space(3))) void*)(lp), 16, 0, 0)

#define PHASE_WAIT(N)                                            \
  asm volatile("s_waitcnt vmcnt(" #N ")" ::: "memory");          \
  __builtin_amdgcn_s_barrier();                                  \
  __builtin_amdgcn_sched_barrier(0)

// ---------------- merged prep kernel ----------------
// One launch covers: bg0/bg1 bias sums, c-state zero, h zero, pad_x, all conv
// weight reorders, fp16 casts, LSTM wcat builds. Segment by global index.
#define POFF0 2048LL        // bg0
#define POFF1 4096LL        // bg1
#define POFF2 135168LL      // c zero (131072 f32)
#define POFF3 266240LL      // h zero (131072 u32)
#define POFF4 5283840LL     // pad_x (5017600)
#define POFF5 5310464LL     // w1r (26624)
#define POFF6 5711872LL     // w2r (401408)
#define POFF7 6531072LL     // w3r (819200)
#define POFF8 9807872LL     // w4r (3276800)
#define POFF9 16361472LL    // w5r (6553600)
#define POFF10 17410048LL   // wih0h (1048576)
#define POFF11 17672192LL   // fw1h (262144)
#define POFF12 18720768LL   // wcat0 (1048576)
#define POFF13 20817920LL   // wcat1 (2097152)  == total

__global__ void prep_all(
    const float* __restrict__ x,
    const float* __restrict__ w1, const float* __restrict__ w2,
    const float* __restrict__ w3, const float* __restrict__ w4,
    const float* __restrict__ w5,
    const float* __restrict__ wih0, const float* __restrict__ whh0,
    const float* __restrict__ bih0, const float* __restrict__ bhh0,
    const float* __restrict__ wih1, const float* __restrict__ whh1,
    const float* __restrict__ bih1, const float* __restrict__ bhh1,
    const float* __restrict__ fw1,
    float* __restrict__ bg0, float* __restrict__ bg1,
    float* __restrict__ czero, unsigned* __restrict__ hzero,
    half_t* __restrict__ xpad,
    half_t* __restrict__ w1r, half_t* __restrict__ w2r, half_t* __restrict__ w3r,
    half_t* __restrict__ w4r, half_t* __restrict__ w5r,
    half_t* __restrict__ wih0h, half_t* __restrict__ fw1h,
    half_t* __restrict__ wcat0h, half_t* __restrict__ wcat1h) {
  long long i = (long long)blockIdx.x * blockDim.x + threadIdx.x;
  if (i < POFF0) {
    bg0[i] = bih0[i] + bhh0[i];
  } else if (i < POFF1) {
    long long j = i - POFF0;
    bg1[j] = bih1[j] + bhh1[j];
  } else if (i < POFF2) {
    czero[i - POFF1] = 0.f;
  } else if (i < POFF3) {
    hzero[i - POFF2] = 0u;
  } else if (i < POFF4) {
    long long j = i - POFF3;
    int c = j & 7;
    long long t = j >> 3;
    int iw = t % 70; t /= 70;
    int ih = t % 70;
    int n = t / 70;
    float v = 0.f;
    if (c < 3 && ih >= 3 && ih < 67 && iw >= 3 && iw < 67)
      v = x[((n * 3 + c) * 64 + (ih - 3)) * 64 + (iw - 3)];
    xpad[j] = f2h(v);
  } else if (i < POFF5) {
    int j = (int)(i - POFF4);
    int kg = j % 416, co = j / 416;
    int ci = kg & 7, tap = kg >> 3;
    float v = 0.f;
    if (tap < 49 && ci < 3) {
      int kh = tap / 7, kw = tap % 7;
      v = w1[((co * 3 + ci) * 7 + kh) * 7 + kw];
    }
    w1r[j] = f2h(v);
  } else if (i < POFF6) {
    int j = (int)(i - POFF5);
    int kg = j % 3136, co = j / 3136;
    int ci = kg & 63, tap = kg >> 6;
    int kh = tap / 7, kw = tap - kh * 7;
    w2r[j] = f2h(w2[((co * 64 + ci) * 7 + kh) * 7 + kw]);
  } else if (i < POFF7) {
    int j = (int)(i - POFF6);
    int kg = j % 3200, co = j / 3200;
    int ci = kg & 127, tap = kg >> 7;
    int kh = tap / 5, kw = tap - kh * 5;
    w3r[j] = f2h(w3[((co * 128 + ci) * 5 + kh) * 5 + kw]);
  } else if (i < POFF8) {
    int j = (int)(i - POFF7);
    int kg = j % 6400, co = j / 6400;
    int ci = kg & 255, tap = kg >> 8;
    int kh = tap / 5, kw = tap - kh * 5;
    w4r[j] = f2h(w4[((co * 256 + ci) * 5 + kh) * 5 + kw]);
  } else if (i < POFF9) {
    int j = (int)(i - POFF8);
    int kg = j % 12800, co = j / 12800;
    int ci = kg & 511, tap = kg >> 9;
    int kh = tap / 5, kw = tap - kh * 5;
    w5r[j] = f2h(w5[((co * 512 + ci) * 5 + kh) * 5 + kw]);
  } else if (i < POFF10) {
    int j = (int)(i - POFF9);
    wih0h[j] = f2h(wih0[j]);
  } else if (i < POFF11) {
    int j = (int)(i - POFF10);
    fw1h[j] = f2h(fw1[j]);
  } else if (i < POFF12) {
    int j = (int)(i - POFF11);
    int r = j >> 9, k = j & 511;
    int u = r >> 2, g = r & 3;
    wcat0h[j] = f2h(whh0[(g * 512 + u) * 512 + k]);
  } else if (i < POFF13) {
    int j = (int)(i - POFF12);
    int r = j >> 10, k = j & 1023;
    int u = r >> 2, g = r & 3;
    int row = g * 512 + u;
    wcat1h[j] = f2h(k < 512 ? wih1[row * 512 + k] : whh1[row * 512 + (k - 512)]);
  }
}

// ---------------- 64x64 fp16 MFMA conv / GEMM ----------------
template <int KW, int S, int LOG2CIN, int OUTMODE>
__global__ __launch_bounds__(256) void conv_mfma(
    const half_t* __restrict__ xin, const half_t* __restrict__ wr,
    const float* __restrict__ bias, void* __restrict__ outp,
    int Hin, int Win, int Hout, int Wout, int Cout, int K, int ktiles, float slope,
    long long zstride) {
  constexpr int CIN = 1 << LOG2CIN;
  __shared__ half_t lds[4][4096];
  const int tid = threadIdx.x;
  const int lane = tid & 63, wid = tid >> 6;
  const int sRow = tid >> 2, sCh = tid & 3;
  const int sSwz = sCh ^ ((sRow ^ (sRow >> 2)) & 3);
  const int kt0 = blockIdx.z * ktiles;
  const half_t* gArow = wr + (size_t)(blockIdx.y * 64 + sRow) * K + sSwz * 8;
  int p = blockIdx.x * 64 + sRow;
  int hw = Hout * Wout;
  int n = p / hw;
  int rem = p - n * hw;
  int oh = rem / Wout;
  int ow = rem - oh * Wout;
  const half_t* xb = xin + ((size_t)(n * Hin + oh * S) * Win + ow * S) * CIN;
  const int fr = lane & 15, fc = lane >> 4;
  const int r0 = (wid & 1) * 32, c0 = (wid >> 1) * 32;
  const int sw = (fc ^ ((fr ^ (fr >> 2)) & 3)) * 8;
  const int ia0 = (r0 + fr) * 32 + sw;
  const int ia1 = (r0 + 16 + fr) * 32 + sw;
  const int ib0 = 2048 + (c0 + fr) * 32 + sw;
  const int ib1 = 2048 + (c0 + 16 + fr) * 32 + sw;

  auto stage = [&](int t, int buf) {
    GLD(gArow + (size_t)(kt0 + t) * 32, &lds[buf][wid * 512]);
    int kg = (kt0 + t) * 32 + sSwz * 8;
    int ci = kg & (CIN - 1);
    int tap = kg >> LOG2CIN;
    int kh = tap / KW, kw = tap - kh * KW;
    GLD(xb + (kh * Win + kw) * CIN + ci, &lds[buf][2048 + wid * 512]);
  };

  f32x4 acc00 = {0.f, 0.f, 0.f, 0.f};
  f32x4 acc01 = acc00, acc10 = acc00, acc11 = acc00;

  auto compute = [&](int buf) {
    const half_t* L = &lds[buf][0];
    f16x8 a0 = *(const f16x8*)&L[ia0];
    f16x8 a1 = *(const f16x8*)&L[ia1];
    f16x8 b0 = *(const f16x8*)&L[ib0];
    f16x8 b1 = *(const f16x8*)&L[ib1];
    acc00 = __builtin_amdgcn_mfma_f32_16x16x32_f16(a0, b0, acc00, 0, 0, 0);
    acc01 = __builtin_amdgcn_mfma_f32_16x16x32_f16(a0, b1, acc01, 0, 0, 0);
    acc10 = __builtin_amdgcn_mfma_f32_16x16x32_f16(a1, b0, acc10, 0, 0, 0);
    acc11 = __builtin_amdgcn_mfma_f32_16x16x32_f16(a1, b1, acc11, 0, 0, 0);
  };

  stage(0, 0);
  stage(1, 1);
  stage(2, 2);
  int t = 0;
  for (; t < ktiles - 3; ++t) {
    PHASE_WAIT(4);
    stage(t + 3, (t + 3) & 3);
    compute(t & 3);
  }
  PHASE_WAIT(4);
  compute(t & 3);
  ++t;
  PHASE_WAIT(2);
  compute(t & 3);
  ++t;
  PHASE_WAIT(0);
  compute(t & 3);

#pragma unroll
  for (int am = 0; am < 2; ++am) {
#pragma unroll
    for (int bn = 0; bn < 2; ++bn) {
      f32x4 a = am == 0 ? (bn == 0 ? acc00 : acc01) : (bn == 0 ? acc10 : acc11);
      int co = blockIdx.y * 64 + r0 + am * 16 + fc * 4;
      int px = blockIdx.x * 64 + c0 + bn * 16 + fr;
      size_t o = (size_t)px * Cout + co;
      if (OUTMODE == 2) {
        float* pb = (float*)outp + (size_t)blockIdx.z * zstride;
        *(f32x4*)&pb[o] = a;
      } else {
        f32x4 bb = *(const f32x4*)&bias[co];
        f32x4 v;
#pragma unroll
        for (int j = 0; j < 4; ++j) {
          float tt = a[j] + bb[j];
          v[j] = LEAKY(tt, slope);
        }
        if (OUTMODE == 1) {
          *(f32x4*)&((float*)outp)[o] = v;
        } else {
          f16x4 hv;
#pragma unroll
          for (int j = 0; j < 4; ++j) hv[j] = f2h(v[j]);
          *(f16x4*)&((half_t*)outp)[o] = hv;
        }
      }
    }
  }
}

// ---------------- 128x128 fp16 MFMA conv (4 waves, 4x4 frags/wave) ----------------
template <int KW, int S, int LOG2CIN, int OUTMODE>
__global__ __launch_bounds__(256) void conv_mfma128(
    const half_t* __restrict__ xin, const half_t* __restrict__ wr,
    const float* __restrict__ bias, void* __restrict__ outp,
    int Hin, int Win, int Hout, int Wout, int Cout, int K, int ktiles, float slope,
    long long zstride) {
  constexpr int CIN = 1 << LOG2CIN;
  __shared__ half_t lds[4][8192];
  const int tid = threadIdx.x;
  const int lane = tid & 63, wid = tid >> 6;
  const int sRow = tid >> 2, sCh = tid & 3;
  const int sSwz = sCh ^ ((sRow ^ (sRow >> 2)) & 3);
  const int kt0 = blockIdx.z * ktiles;
  const half_t* gA0 = wr + (size_t)(blockIdx.y * 128 + sRow) * K + sSwz * 8;
  const half_t* gA1 = wr + (size_t)(blockIdx.y * 128 + 64 + sRow) * K + sSwz * 8;
  int hw = Hout * Wout;
  int p0 = blockIdx.x * 128 + sRow;
  int n0 = p0 / hw, r0p = p0 - n0 * hw, oh0 = r0p / Wout, ow0 = r0p - oh0 * Wout;
  const half_t* xb0 = xin + ((size_t)(n0 * Hin + oh0 * S) * Win + ow0 * S) * CIN;
  int p1 = p0 + 64;
  int n1 = p1 / hw, r1p = p1 - n1 * hw, oh1 = r1p / Wout, ow1 = r1p - oh1 * Wout;
  const half_t* xb1 = xin + ((size_t)(n1 * Hin + oh1 * S) * Win + ow1 * S) * CIN;

  const int fr = lane & 15, fc = lane >> 4;
  const int wr_ = wid & 1, wc_ = wid >> 1;
  const int sw = (fc ^ ((fr ^ (fr >> 2)) & 3)) * 8;
  const int iaB = (wr_ * 64 + fr) * 32 + sw;
  const int ibB = 4096 + (wc_ * 64 + fr) * 32 + sw;

  auto stage = [&](int t, int buf) {
    half_t* LB = &lds[buf][0];
    GLD(gA0 + (size_t)(kt0 + t) * 32, LB + wid * 512);
    GLD(gA1 + (size_t)(kt0 + t) * 32, LB + 2048 + wid * 512);
    int kg = (kt0 + t) * 32 + sSwz * 8;
    int ci = kg & (CIN - 1);
    int tap = kg >> LOG2CIN;
    int kh = tap / KW, kw = tap - kh * KW;
    int xoff = (kh * Win + kw) * CIN + ci;
    GLD(xb0 + xoff, LB + 4096 + wid * 512);
    GLD(xb1 + xoff, LB + 6144 + wid * 512);
  };

  f32x4 acc[4][4];
#pragma unroll
  for (int i = 0; i < 4; ++i)
#pragma unroll
    for (int j = 0; j < 4; ++j) acc[i][j] = (f32x4){0.f, 0.f, 0.f, 0.f};

  auto compute = [&](int buf) {
    const half_t* L = &lds[buf][0];
    f16x8 a[4], b[4];
#pragma unroll
    for (int fi = 0; fi < 4; ++fi) a[fi] = *(const f16x8*)&L[iaB + fi * 512];
#pragma unroll
    for (int fj = 0; fj < 4; ++fj) b[fj] = *(const f16x8*)&L[ibB + fj * 512];
#pragma unroll
    for (int fi = 0; fi < 4; ++fi)
#pragma unroll
      for (int fj = 0; fj < 4; ++fj)
        acc[fi][fj] = __builtin_amdgcn_mfma_f32_16x16x32_f16(a[fi], b[fj], acc[fi][fj], 0, 0, 0);
  };

  stage(0, 0);
  stage(1, 1);
  stage(2, 2);
  int t = 0;
  for (; t < ktiles - 3; ++t) {
    PHASE_WAIT(8);
    stage(t + 3, (t + 3) & 3);
    compute(t & 3);
  }
  PHASE_WAIT(8);
  compute(t & 3);
  ++t;
  PHASE_WAIT(4);
  compute(t & 3);
  ++t;
  PHASE_WAIT(0);
  compute(t & 3);

#pragma unroll
  for (int fi = 0; fi < 4; ++fi) {
#pragma unroll
    for (int fj = 0; fj < 4; ++fj) {
      int co = blockIdx.y * 128 + wr_ * 64 + fi * 16 + fc * 4;
      int px = blockIdx.x * 128 + wc_ * 64 + fj * 16 + fr;
      size_t o = (size_t)px * Cout + co;
      if (OUTMODE == 2) {
        float* pb = (float*)outp + (size_t)blockIdx.z * zstride;
        *(f32x4*)&pb[o] = acc[fi][fj];
      } else {
        f32x4 bb = *(const f32x4*)&bias[co];
        f16x4 hv;
#pragma unroll
        for (int j = 0; j < 4; ++j) {
          float tt = acc[fi][fj][j] + bb[j];
          hv[j] = f2h(LEAKY(tt, slope));
        }
        *(f16x4*)&((half_t*)outp)[o] = hv;
      }
    }
  }
}

// reduce K-split f32 partials
__global__ void finalize_part(const float* __restrict__ pb, const float* __restrict__ bias,
                              half_t* __restrict__ out, int size, int nz) {
  int i = blockIdx.x * blockDim.x + threadIdx.x;
  if (i >= size) return;
  float s = bias[i & 511];
  for (int z = 0; z < nz; ++z) s += pb[(size_t)z * size + i];
  out[i] = f2h(LEAKY(s, 0.2f));
}

// ---------------- fused LSTM step: layer0(t+1) || layer1(t) (round-5 proven) ----
__global__ __launch_bounds__(256) void lstm_fused(
    const half_t* __restrict__ h0in, half_t* __restrict__ h0out,
    const half_t* __restrict__ h1in, half_t* __restrict__ h1out,
    const half_t* __restrict__ wcat0, const half_t* __restrict__ wcat1,
    const float* __restrict__ xw0, const float* __restrict__ bg1,
    float* __restrict__ c0, float* __restrict__ c1,
    half_t* __restrict__ ysout, int roles) {
  const bool isL1 = (roles == 2) || (blockIdx.z == 1);
  const int KT = isL1 ? 32 : 16;
  const half_t* wcat = isL1 ? wcat1 : wcat0;
  const half_t* hB = h1in;
  float* c = isL1 ? c1 : c0;
  half_t* hout = isL1 ? h1out : h0out;
  const int K = KT * 32;

  __shared__ half_t lds[4][4096];
  const int tid = threadIdx.x;
  const int lane = tid & 63, wid = tid >> 6;
  const int sRow = tid >> 2, sCh = tid & 3;
  const int sSwz = sCh ^ ((sRow ^ (sRow >> 2)) & 3);
  const half_t* gArow = wcat + (size_t)(blockIdx.y * 64 + sRow) * K + sSwz * 8;
  const int bb = blockIdx.x * 64 + sRow;
  const int fr = lane & 15, fc = lane >> 4;
  const int r0 = (wid & 1) * 32, c0w = (wid >> 1) * 32;
  const int sw = (fc ^ ((fr ^ (fr >> 2)) & 3)) * 8;
  const int ia0 = (r0 + fr) * 32 + sw;
  const int ia1 = (r0 + 16 + fr) * 32 + sw;
  const int ib0 = 2048 + (c0w + fr) * 32 + sw;
  const int ib1 = 2048 + (c0w + 16 + fr) * 32 + sw;

  auto stage = [&](int t, int buf) {
    GLD(gArow + (size_t)t * 32, &lds[buf][wid * 512]);
    int kg = t * 32 + sSwz * 8;
    const half_t* hsrc = (kg < 512) ? h0in : hB;
    GLD(hsrc + bb * 512 + (kg & 511), &lds[buf][2048 + wid * 512]);
  };

  f32x4 acc00 = {0.f, 0.f, 0.f, 0.f};
  f32x4 acc01 = acc00, acc10 = acc00, acc11 = acc00;

  auto compute = [&](int buf) {
    const half_t* L = &lds[buf][0];
    f16x8 a0 = *(const f16x8*)&L[ia0];
    f16x8 a1 = *(const f16x8*)&L[ia1];
    f16x8 b0 = *(const f16x8*)&L[ib0];
    f16x8 b1 = *(const f16x8*)&L[ib1];
    acc00 = __builtin_amdgcn_mfma_f32_16x16x32_f16(a0, b0, acc00, 0, 0, 0);
    acc01 = __builtin_amdgcn_mfma_f32_16x16x32_f16(a0, b1, acc01, 0, 0, 0);
    acc10 = __builtin_amdgcn_mfma_f32_16x16x32_f16(a1, b0, acc10, 0, 0, 0);
    acc11 = __builtin_amdgcn_mfma_f32_16x16x32_f16(a1, b1, acc11, 0, 0, 0);
  };

  stage(0, 0);
  stage(1, 1);
  stage(2, 2);
  int t = 0;
  for (; t < KT - 3; ++t) {
    PHASE_WAIT(4);
    stage(t + 3, (t + 3) & 3);
    compute(t & 3);
  }
  PHASE_WAIT(4);
  compute(t & 3);
  ++t;
  PHASE_WAIT(2);
  compute(t & 3);
  ++t;
  PHASE_WAIT(0);
  compute(t & 3);

#pragma unroll
  for (int am = 0; am < 2; ++am) {
#pragma unroll
    for (int bn = 0; bn < 2; ++bn) {
      f32x4 a = am == 0 ? (bn == 0 ? acc00 : acc01) : (bn == 0 ? acc10 : acc11);
      int Rb = blockIdx.y * 64 + r0 + am * 16 + fc * 4;
      int u = Rb >> 2;
      int b = blockIdx.x * 64 + c0w + bn * 16 + fr;
      float p[4];
#pragma unroll
      for (int j = 0; j < 4; ++j) {
        float s = a[j];
        s += isL1 ? bg1[j * 512 + u] : xw0[b * 2048 + j * 512 + u];
        p[j] = s;
      }
      int ci = b * 512 + u;
      float cprev = c[ci];
      float ig = sig_(p[0]);
      float fg = sig_(p[1]);
      float gg = tanhf(p[2]);
      float og = sig_(p[3]);
      float cn = fg * cprev + ig * gg;
      float hn = og * tanhf(cn);
      c[ci] = cn;
      hout[ci] = f2h(hn);
      if (isL1) ysout[ci] = f2h(hn);
    }
  }
}

// ---------------- final FC: sigmoid(fc1o @ fw2.T + fb2), [2560,13] ----------------
__global__ void fc2_sigmoid(const half_t* __restrict__ in, const float* __restrict__ w,
                            const float* __restrict__ b, float* __restrict__ out) {
  int idx = blockIdx.x * blockDim.x + threadIdx.x;
  if (idx >= 2560 * 13) return;
  int j = idx % 13, r = idx / 13;
  const half_t* ip = in + (size_t)r * 512;
  const float* wp = w + j * 512;
  float s = b[j];
  for (int k = 0; k < 512; k += 8) {
    f16x8 hv = *(const f16x8*)&ip[k];
#pragma unroll
    for (int q = 0; q < 8; ++q) s = fmaf((float)hv[q], wp[k + q], s);
  }
  out[idx] = sig_(s);
}

// ---------------- launch ----------------
extern "C" void kernel_launch(void* const* d_in, const int* in_sizes, int n_in,
                              void* d_out, int out_size, void* d_ws, size_t ws_size,
                              hipStream_t stream) {
  const float* x   = (const float*)d_in[0];
  const float* w1  = (const float*)d_in[1];  const float* b1 = (const float*)d_in[2];
  const float* w2  = (const float*)d_in[3];  const float* b2 = (const float*)d_in[4];
  const float* w3  = (const float*)d_in[5];  const float* b3 = (const float*)d_in[6];
  const float* w4  = (const float*)d_in[7];  const float* b4 = (const float*)d_in[8];
  const float* w5  = (const float*)d_in[9];  const float* b5 = (const float*)d_in[10];
  const float* wih0 = (const float*)d_in[11]; const float* whh0 = (const float*)d_in[12];
  const float* bih0 = (const float*)d_in[13]; const float* bhh0 = (const float*)d_in[14];
  const float* wih1 = (const float*)d_in[15]; const float* whh1 = (const float*)d_in[16];
  const float* bih1 = (const float*)d_in[17]; const float* bhh1 = (const float*)d_in[18];
  const float* fw1 = (const float*)d_in[19]; const float* fb1 = (const float*)d_in[20];
  const float* fw2 = (const float*)d_in[21]; const float* fb2 = (const float*)d_in[22];
  float* out = (float*)d_out;

  // ---- workspace layout (~68.6 MB; 75.6 MB proven safe) ----
  float* bg0 = (float*)d_ws;                // 2048
  float* bg1 = bg0 + 2048;                  // 2048
  float* xw0 = bg1 + 2048;                  // 262144
  float* c0  = xw0 + 262144;                // 65536
  float* c1  = c0 + 65536;                  // 65536
  half_t* h0a = (half_t*)(c1 + 65536);      // 4 x 65536 halves
  half_t* h0b = h0a + 65536;
  half_t* h1a = h0b + 65536;
  half_t* h1b = h1a + 65536;
  half_t* BUF1 = h1b + 65536;               // 8,388,608  [A1 -> A3 -> feat]
  half_t* BUF2 = BUF1 + 8388608;            // 2,768,896  [A2 -> A4 -> ys+fc1o]
  half_t* w1r  = BUF2 + 2768896;            // 26,624
  half_t* w2r  = w1r + 26624;               // 401,408
  half_t* w3r  = w2r + 401408;              // 819,200
  half_t* w4r  = w3r + 819200;              // 3,276,800
  half_t* w5r  = w4r + 3276800;             // 6,553,600
  half_t* wih0h  = w5r + 6553600;           // 1,048,576
  half_t* wcat0h = wih0h + 1048576;         // 1,048,576
  half_t* wcat1h = wcat0h + 1048576;        // 2,097,152
  half_t* fw1h   = wcat1h + 2097152;        // 262,144
  half_t* xpad   = fw1h + 262144;           // union: xpad 5,017,600 h / pbC 3,276,800 f32
  float* pbC = (float*)xpad;

  half_t* A1 = BUF1;                        // [131072 px][64]
  half_t* A2 = BUF2;                        // [21632][128]
  half_t* A3 = BUF1;                        // [10368][256]
  half_t* A4 = BUF2;                        // [3200][512]  (A2 dead)
  half_t* feat = BUF1;                      // [128][512]   (A3 dead)
  half_t* ys   = BUF2;                      // [2560][512]  (A4 dead post-conv5)
  half_t* fc1o = BUF2 + 1310720;

  dim3 blk(256);

  // ---- merged prep (one launch) ----
  prep_all<<<81320, blk, 0, stream>>>(
      x, w1, w2, w3, w4, w5, wih0, whh0, bih0, bhh0, wih1, whh1, bih1, bhh1, fw1,
      bg0, bg1, c0, (unsigned*)h0a, xpad, w1r, w2r, w3r, w4r, w5r,
      wih0h, fw1h, wcat0h, wcat1h);

  // ---- conv stack ----
  conv_mfma<7, 2, 3, 0><<<dim3(2048, 1, 1), blk, 0, stream>>>(
      xpad, w1r, b1, A1, 70, 70, 32, 32, 64, 416, 13, 0.2f, 0);
  conv_mfma128<7, 2, 6, 0><<<dim3(169, 1, 1), blk, 0, stream>>>(
      A1, w2r, b2, A2, 32, 32, 13, 13, 128, 3136, 98, 0.2f, 0);
  conv_mfma128<5, 1, 7, 0><<<dim3(81, 2, 1), blk, 0, stream>>>(
      A2, w3r, b3, A3, 13, 13, 9, 9, 256, 3200, 100, 0.2f, 0);
  conv_mfma128<5, 1, 8, 2><<<dim3(25, 4, 2), blk, 0, stream>>>(
      A3, w4r, b4, pbC, 9, 9, 5, 5, 512, 6400, 100, 0.2f, (long long)3200 * 512);
  finalize_part<<<6400, blk, 0, stream>>>(pbC, b4, A4, 1638400, 2);
  conv_mfma<5, 1, 9, 2><<<dim3(2, 8, 25), blk, 0, stream>>>(
      A4, w5r, b5, pbC, 5, 5, 1, 1, 512, 12800, 16, 0.2f, (long long)65536);
  finalize_part<<<256, blk, 0, stream>>>(pbC, b5, feat, 65536, 25);

  // xw0 = feat @ wih0.T + bg0  [128][2048] f32 (slope=1 -> identity)
  conv_mfma<1, 1, 9, 1><<<dim3(2, 32, 1), blk, 0, stream>>>(
      feat, wih0h, bg0, xw0, 1, 1, 1, 1, 2048, 512, 16, 1.0f, 0);

  // ---- 2-layer LSTM, 20 steps, fused l0(t+1)||l1(t): 21 launches ----
  half_t* h0buf[2] = {h0a, h0b};
  half_t* h1buf[2] = {h1a, h1b};
  lstm_fused<<<dim3(2, 32, 1), blk, 0, stream>>>(
      h0a, h0b, h1a, h1a, wcat0h, wcat1h, xw0, bg1, c0, c1, ys, 1);
  for (int t = 2; t <= 20; ++t) {
    lstm_fused<<<dim3(2, 32, 2), blk, 0, stream>>>(
        h0buf[(t - 1) & 1], h0buf[t & 1], h1buf[t & 1], h1buf[(t - 1) & 1],
        wcat0h, wcat1h, xw0, bg1, c0, c1, ys + (size_t)(t - 2) * 65536, 3);
  }
  lstm_fused<<<dim3(2, 32, 1), blk, 0, stream>>>(
      h0buf[0], h0buf[1], h1buf[1], h1buf[0],
      wcat0h, wcat1h, xw0, bg1, c0, c1, ys + (size_t)19 * 65536, 2);

  // ---- FC head ----
  conv_mfma<1, 1, 9, 0><<<dim3(40, 8, 1), blk, 0, stream>>>(
      ys, fw1h, fb1, fc1o, 1, 1, 1, 1, 512, 512, 16, 0.01f, 0);
  fc2_sigmoid<<<130, blk, 0, stream>>>(fc1o, fw2, fb2, out);
}

// Round 8
// 411.832 us; speedup vs baseline: 1.7600x; 1.2183x over previous
//
#include <hip/hip_runtime.h>
#include <math.h>

typedef _Float16 half_t;
typedef __attribute__((ext_vector_type(8))) _Float16 f16x8;
typedef __attribute__((ext_vector_type(4))) _Float16 f16x4;
typedef __attribute__((ext_vector_type(4))) float f32x4;

#define LEAKY(v, s) ((v) >= 0.f ? (v) : (s) * (v))

__device__ __forceinline__ float sig_(float x) { return 1.f / (1.f + expf(-x)); }
__device__ __forceinline__ half_t f2h(float f) { return (half_t)f; }

#define GLD(gp, lp)                                              \
  __builtin_amdgcn_global_load_lds(                              \
      (const __attribute__((address_space(1))) void*)(gp),       \
      (__attribute__((address_space(3))) void*)(lp), 16, 0, 0)

#define PHASE_WAIT(N)                                            \
  asm volatile("s_waitcnt vmcnt(" #N ")" ::: "memory");          \
  __builtin_amdgcn_s_barrier();                                  \
  __builtin_amdgcn_sched_barrier(0)

// ---------------- merged elementwise prep ----------------
// Segments: bg0, bg1, c-zero, h-zero, pad_x, w1r, wih0h, fw1h, wcat0, wcat1.
#define QOFF0 2048LL
#define QOFF1 4096LL
#define QOFF2 135168LL
#define QOFF3 266240LL
#define QOFF4 5283840LL
#define QOFF5 5310464LL
#define QOFF6 6359040LL
#define QOFF7 6621184LL
#define QOFF8 7669760LL
#define QOFF9 9766912LL   // total

__global__ void prep_all(
    const float* __restrict__ x, const float* __restrict__ w1,
    const float* __restrict__ wih0, const float* __restrict__ whh0,
    const float* __restrict__ bih0, const float* __restrict__ bhh0,
    const float* __restrict__ wih1, const float* __restrict__ whh1,
    const float* __restrict__ bih1, const float* __restrict__ bhh1,
    const float* __restrict__ fw1,
    float* __restrict__ bg0, float* __restrict__ bg1,
    float* __restrict__ czero, unsigned* __restrict__ hzero,
    half_t* __restrict__ xpad, half_t* __restrict__ w1r,
    half_t* __restrict__ wih0h, half_t* __restrict__ fw1h,
    half_t* __restrict__ wcat0h, half_t* __restrict__ wcat1h) {
  long long i = (long long)blockIdx.x * blockDim.x + threadIdx.x;
  if (i < QOFF0) {
    bg0[i] = bih0[i] + bhh0[i];
  } else if (i < QOFF1) {
    long long j = i - QOFF0;
    bg1[j] = bih1[j] + bhh1[j];
  } else if (i < QOFF2) {
    czero[i - QOFF1] = 0.f;
  } else if (i < QOFF3) {
    hzero[i - QOFF2] = 0u;
  } else if (i < QOFF4) {
    long long j = i - QOFF3;
    int c = j & 7;
    long long t = j >> 3;
    int iw = t % 70; t /= 70;
    int ih = t % 70;
    int n = t / 70;
    float v = 0.f;
    if (c < 3 && ih >= 3 && ih < 67 && iw >= 3 && iw < 67)
      v = x[((n * 3 + c) * 64 + (ih - 3)) * 64 + (iw - 3)];
    xpad[j] = f2h(v);
  } else if (i < QOFF5) {
    int j = (int)(i - QOFF4);
    int kg = j % 416, co = j / 416;
    int ci = kg & 7, tap = kg >> 3;
    float v = 0.f;
    if (tap < 49 && ci < 3) {
      int kh = tap / 7, kw = tap % 7;
      v = w1[((co * 3 + ci) * 7 + kh) * 7 + kw];
    }
    w1r[j] = f2h(v);
  } else if (i < QOFF6) {
    int j = (int)(i - QOFF5);
    wih0h[j] = f2h(wih0[j]);
  } else if (i < QOFF7) {
    int j = (int)(i - QOFF6);
    fw1h[j] = f2h(fw1[j]);
  } else if (i < QOFF8) {
    int j = (int)(i - QOFF7);
    int r = j >> 9, k = j & 511;
    int u = r >> 2, g = r & 3;
    wcat0h[j] = f2h(whh0[(g * 512 + u) * 512 + k]);
  } else if (i < QOFF9) {
    int j = (int)(i - QOFF8);
    int r = j >> 10, k = j & 1023;
    int u = r >> 2, g = r & 3;
    int row = g * 512 + u;
    wcat1h[j] = f2h(k < 512 ? wih1[row * 512 + k] : whh1[row * 512 + (k - 512)]);
  }
}

// ---------------- LDS-bounce weight transpose (coalesced both ways) ----------------
// One block per co row: read [Cin][TAP] f32 coalesced -> LDS -> write
// [TAP][Cin] fp16 coalesced. Blocks: w2 128 | w3 256 | w4 512 | w5 512.
__global__ __launch_bounds__(256) void prep_wT(
    const float* __restrict__ w2, const float* __restrict__ w3,
    const float* __restrict__ w4, const float* __restrict__ w5,
    half_t* __restrict__ w2r, half_t* __restrict__ w3r,
    half_t* __restrict__ w4r, half_t* __restrict__ w5r) {
  __shared__ float T[12800];  // 51.2 KB (max panel: w5 512x25)
  int bid = blockIdx.x, tid = threadIdx.x;
  const float* W;
  half_t* D;
  int co, Cin, TAP, lg2;
  if (bid < 128) {
    W = w2; D = w2r; co = bid; Cin = 64; TAP = 49; lg2 = 6;
  } else if (bid < 384) {
    W = w3; D = w3r; co = bid - 128; Cin = 128; TAP = 25; lg2 = 7;
  } else if (bid < 896) {
    W = w4; D = w4r; co = bid - 384; Cin = 256; TAP = 25; lg2 = 8;
  } else {
    W = w5; D = w5r; co = bid - 896; Cin = 512; TAP = 25; lg2 = 9;
  }
  int n = Cin * TAP;
  const float* src = W + (size_t)co * n;
  for (int i = tid; i < n; i += 256) T[i] = src[i];
  __syncthreads();
  half_t* dst = D + (size_t)co * n;
  for (int j = tid; j < n; j += 256) {
    int ci = j & (Cin - 1);
    int tap = j >> lg2;
    dst[j] = f2h(T[ci * TAP + tap]);
  }
}

// ---------------- 64x64 fp16 MFMA conv / GEMM ----------------
template <int KW, int S, int LOG2CIN, int OUTMODE>
__global__ __launch_bounds__(256) void conv_mfma(
    const half_t* __restrict__ xin, const half_t* __restrict__ wr,
    const float* __restrict__ bias, void* __restrict__ outp,
    int Hin, int Win, int Hout, int Wout, int Cout, int K, int ktiles, float slope,
    long long zstride) {
  constexpr int CIN = 1 << LOG2CIN;
  __shared__ half_t lds[4][4096];
  const int tid = threadIdx.x;
  const int lane = tid & 63, wid = tid >> 6;
  const int sRow = tid >> 2, sCh = tid & 3;
  const int sSwz = sCh ^ ((sRow ^ (sRow >> 2)) & 3);
  const int kt0 = blockIdx.z * ktiles;
  const half_t* gArow = wr + (size_t)(blockIdx.y * 64 + sRow) * K + sSwz * 8;
  int p = blockIdx.x * 64 + sRow;
  int hw = Hout * Wout;
  int n = p / hw;
  int rem = p - n * hw;
  int oh = rem / Wout;
  int ow = rem - oh * Wout;
  const half_t* xb = xin + ((size_t)(n * Hin + oh * S) * Win + ow * S) * CIN;
  const int fr = lane & 15, fc = lane >> 4;
  const int r0 = (wid & 1) * 32, c0 = (wid >> 1) * 32;
  const int sw = (fc ^ ((fr ^ (fr >> 2)) & 3)) * 8;
  const int ia0 = (r0 + fr) * 32 + sw;
  const int ia1 = (r0 + 16 + fr) * 32 + sw;
  const int ib0 = 2048 + (c0 + fr) * 32 + sw;
  const int ib1 = 2048 + (c0 + 16 + fr) * 32 + sw;

  auto stage = [&](int t, int buf) {
    GLD(gArow + (size_t)(kt0 + t) * 32, &lds[buf][wid * 512]);
    int kg = (kt0 + t) * 32 + sSwz * 8;
    int ci = kg & (CIN - 1);
    int tap = kg >> LOG2CIN;
    int kh = tap / KW, kw = tap - kh * KW;
    GLD(xb + (kh * Win + kw) * CIN + ci, &lds[buf][2048 + wid * 512]);
  };

  f32x4 acc00 = {0.f, 0.f, 0.f, 0.f};
  f32x4 acc01 = acc00, acc10 = acc00, acc11 = acc00;

  auto compute = [&](int buf) {
    const half_t* L = &lds[buf][0];
    f16x8 a0 = *(const f16x8*)&L[ia0];
    f16x8 a1 = *(const f16x8*)&L[ia1];
    f16x8 b0 = *(const f16x8*)&L[ib0];
    f16x8 b1 = *(const f16x8*)&L[ib1];
    acc00 = __builtin_amdgcn_mfma_f32_16x16x32_f16(a0, b0, acc00, 0, 0, 0);
    acc01 = __builtin_amdgcn_mfma_f32_16x16x32_f16(a0, b1, acc01, 0, 0, 0);
    acc10 = __builtin_amdgcn_mfma_f32_16x16x32_f16(a1, b0, acc10, 0, 0, 0);
    acc11 = __builtin_amdgcn_mfma_f32_16x16x32_f16(a1, b1, acc11, 0, 0, 0);
  };

  stage(0, 0);
  stage(1, 1);
  stage(2, 2);
  int t = 0;
  for (; t < ktiles - 3; ++t) {
    PHASE_WAIT(4);
    stage(t + 3, (t + 3) & 3);
    compute(t & 3);
  }
  PHASE_WAIT(4);
  compute(t & 3);
  ++t;
  PHASE_WAIT(2);
  compute(t & 3);
  ++t;
  PHASE_WAIT(0);
  compute(t & 3);

#pragma unroll
  for (int am = 0; am < 2; ++am) {
#pragma unroll
    for (int bn = 0; bn < 2; ++bn) {
      f32x4 a = am == 0 ? (bn == 0 ? acc00 : acc01) : (bn == 0 ? acc10 : acc11);
      int co = blockIdx.y * 64 + r0 + am * 16 + fc * 4;
      int px = blockIdx.x * 64 + c0 + bn * 16 + fr;
      size_t o = (size_t)px * Cout + co;
      if (OUTMODE == 2) {
        float* pb = (float*)outp + (size_t)blockIdx.z * zstride;
        *(f32x4*)&pb[o] = a;
      } else {
        f32x4 bb = *(const f32x4*)&bias[co];
        f32x4 v;
#pragma unroll
        for (int j = 0; j < 4; ++j) {
          float tt = a[j] + bb[j];
          v[j] = LEAKY(tt, slope);
        }
        if (OUTMODE == 1) {
          *(f32x4*)&((float*)outp)[o] = v;
        } else {
          f16x4 hv;
#pragma unroll
          for (int j = 0; j < 4; ++j) hv[j] = f2h(v[j]);
          *(f16x4*)&((half_t*)outp)[o] = hv;
        }
      }
    }
  }
}

// ---------------- 128x128 fp16 MFMA conv (4 waves, 4x4 frags/wave) ----------------
template <int KW, int S, int LOG2CIN, int OUTMODE>
__global__ __launch_bounds__(256) void conv_mfma128(
    const half_t* __restrict__ xin, const half_t* __restrict__ wr,
    const float* __restrict__ bias, void* __restrict__ outp,
    int Hin, int Win, int Hout, int Wout, int Cout, int K, int ktiles, float slope,
    long long zstride) {
  constexpr int CIN = 1 << LOG2CIN;
  __shared__ half_t lds[4][8192];
  const int tid = threadIdx.x;
  const int lane = tid & 63, wid = tid >> 6;
  const int sRow = tid >> 2, sCh = tid & 3;
  const int sSwz = sCh ^ ((sRow ^ (sRow >> 2)) & 3);
  const int kt0 = blockIdx.z * ktiles;
  const half_t* gA0 = wr + (size_t)(blockIdx.y * 128 + sRow) * K + sSwz * 8;
  const half_t* gA1 = wr + (size_t)(blockIdx.y * 128 + 64 + sRow) * K + sSwz * 8;
  int hw = Hout * Wout;
  int p0 = blockIdx.x * 128 + sRow;
  int n0 = p0 / hw, r0p = p0 - n0 * hw, oh0 = r0p / Wout, ow0 = r0p - oh0 * Wout;
  const half_t* xb0 = xin + ((size_t)(n0 * Hin + oh0 * S) * Win + ow0 * S) * CIN;
  int p1 = p0 + 64;
  int n1 = p1 / hw, r1p = p1 - n1 * hw, oh1 = r1p / Wout, ow1 = r1p - oh1 * Wout;
  const half_t* xb1 = xin + ((size_t)(n1 * Hin + oh1 * S) * Win + ow1 * S) * CIN;

  const int fr = lane & 15, fc = lane >> 4;
  const int wr_ = wid & 1, wc_ = wid >> 1;
  const int sw = (fc ^ ((fr ^ (fr >> 2)) & 3)) * 8;
  const int iaB = (wr_ * 64 + fr) * 32 + sw;
  const int ibB = 4096 + (wc_ * 64 + fr) * 32 + sw;

  auto stage = [&](int t, int buf) {
    half_t* LB = &lds[buf][0];
    GLD(gA0 + (size_t)(kt0 + t) * 32, LB + wid * 512);
    GLD(gA1 + (size_t)(kt0 + t) * 32, LB + 2048 + wid * 512);
    int kg = (kt0 + t) * 32 + sSwz * 8;
    int ci = kg & (CIN - 1);
    int tap = kg >> LOG2CIN;
    int kh = tap / KW, kw = tap - kh * KW;
    int xoff = (kh * Win + kw) * CIN + ci;
    GLD(xb0 + xoff, LB + 4096 + wid * 512);
    GLD(xb1 + xoff, LB + 6144 + wid * 512);
  };

  f32x4 acc[4][4];
#pragma unroll
  for (int i = 0; i < 4; ++i)
#pragma unroll
    for (int j = 0; j < 4; ++j) acc[i][j] = (f32x4){0.f, 0.f, 0.f, 0.f};

  auto compute = [&](int buf) {
    const half_t* L = &lds[buf][0];
    f16x8 a[4], b[4];
#pragma unroll
    for (int fi = 0; fi < 4; ++fi) a[fi] = *(const f16x8*)&L[iaB + fi * 512];
#pragma unroll
    for (int fj = 0; fj < 4; ++fj) b[fj] = *(const f16x8*)&L[ibB + fj * 512];
#pragma unroll
    for (int fi = 0; fi < 4; ++fi)
#pragma unroll
      for (int fj = 0; fj < 4; ++fj)
        acc[fi][fj] = __builtin_amdgcn_mfma_f32_16x16x32_f16(a[fi], b[fj], acc[fi][fj], 0, 0, 0);
  };

  stage(0, 0);
  stage(1, 1);
  stage(2, 2);
  int t = 0;
  for (; t < ktiles - 3; ++t) {
    PHASE_WAIT(8);
    stage(t + 3, (t + 3) & 3);
    compute(t & 3);
  }
  PHASE_WAIT(8);
  compute(t & 3);
  ++t;
  PHASE_WAIT(4);
  compute(t & 3);
  ++t;
  PHASE_WAIT(0);
  compute(t & 3);

#pragma unroll
  for (int fi = 0; fi < 4; ++fi) {
#pragma unroll
    for (int fj = 0; fj < 4; ++fj) {
      int co = blockIdx.y * 128 + wr_ * 64 + fi * 16 + fc * 4;
      int px = blockIdx.x * 128 + wc_ * 64 + fj * 16 + fr;
      size_t o = (size_t)px * Cout + co;
      if (OUTMODE == 2) {
        float* pb = (float*)outp + (size_t)blockIdx.z * zstride;
        *(f32x4*)&pb[o] = acc[fi][fj];
      } else {
        f32x4 bb = *(const f32x4*)&bias[co];
        f16x4 hv;
#pragma unroll
        for (int j = 0; j < 4; ++j) {
          float tt = acc[fi][fj][j] + bb[j];
          hv[j] = f2h(LEAKY(tt, slope));
        }
        *(f16x4*)&((half_t*)outp)[o] = hv;
      }
    }
  }
}

// reduce K-split f32 partials
__global__ void finalize_part(const float* __restrict__ pb, const float* __restrict__ bias,
                              half_t* __restrict__ out, int size, int nz) {
  int i = blockIdx.x * blockDim.x + threadIdx.x;
  if (i >= size) return;
  float s = bias[i & 511];
  for (int z = 0; z < nz; ++z) s += pb[(size_t)z * size + i];
  out[i] = f2h(LEAKY(s, 0.2f));
}

// ---------------- fused LSTM step, BK=64: layer0(t+1) || layer1(t) ----------------
// A = wcat rows (64), B = batch (64), K tiles of 64. 8-way XOR chunk swizzle
// (slot ch holds src chunk ch^(row&7)) via pre-swizzled global source; ds_read
// applies the same XOR. Depth-4 pipeline, counted vmcnt (4 GLD/thread/stage).
__global__ __launch_bounds__(256) void lstm_fused(
    const half_t* __restrict__ h0in, half_t* __restrict__ h0out,
    const half_t* __restrict__ h1in, half_t* __restrict__ h1out,
    const half_t* __restrict__ wcat0, const half_t* __restrict__ wcat1,
    const float* __restrict__ xw0, const float* __restrict__ bg1,
    float* __restrict__ c0, float* __restrict__ c1,
    half_t* __restrict__ ysout, int roles) {
  const bool isL1 = (roles == 2) || (blockIdx.z == 1);
  const int NT = isL1 ? 16 : 8;  // K/64
  const half_t* wcat = isL1 ? wcat1 : wcat0;
  float* c = isL1 ? c1 : c0;
  half_t* hout = isL1 ? h1out : h0out;
  const int K = NT * 64;

  __shared__ half_t lds[4][8192];  // per buf: A[64][64] at 0, B[64][64] at 4096
  const int tid = threadIdx.x;
  const int lane = tid & 63, wid = tid >> 6;
  const int ybase = blockIdx.y * 64, bbase = blockIdx.x * 64;
  // staging: thread covers chunks q0=wid*128+lane, q1=q0+64 for A and B.
  const int rA0 = wid * 16 + (lane >> 3);
  const int rA1 = rA0 + 8;
  const int chS = ((lane & 7) ^ ((lane >> 3) & 7)) * 8;
  const half_t* gA0 = wcat + (size_t)(ybase + rA0) * K + chS;
  const half_t* gA1 = wcat + (size_t)(ybase + rA1) * K + chS;
  const size_t hb0 = (size_t)(bbase + rA0) * 512 + chS;
  const size_t hb1 = (size_t)(bbase + rA1) * 512 + chS;

  auto stage = [&](int t, int buf) {
    GLD(gA0 + t * 64, &lds[buf][wid * 1024]);
    GLD(gA1 + t * 64, &lds[buf][wid * 1024 + 512]);
    const half_t* hs = (isL1 && t >= 8) ? h1in : h0in;
    int koff = (isL1 && t >= 8) ? (t - 8) * 64 : t * 64;
    GLD(hs + hb0 + koff, &lds[buf][4096 + wid * 1024]);
    GLD(hs + hb1 + koff, &lds[buf][4096 + wid * 1024 + 512]);
  };

  const int fr = lane & 15, fc = lane >> 4;
  const int wr_ = wid & 1, wc_ = wid >> 1;

  f32x4 acc[2][2];
#pragma unroll
  for (int fi = 0; fi < 2; ++fi)
#pragma unroll
    for (int fj = 0; fj < 2; ++fj) acc[fi][fj] = (f32x4){0.f, 0.f, 0.f, 0.f};

  auto compute = [&](int buf) {
    const half_t* L = &lds[buf][0];
#pragma unroll
    for (int s = 0; s < 2; ++s) {
      f16x8 a[2], b[2];
#pragma unroll
      for (int fi = 0; fi < 2; ++fi) {
        int row = wr_ * 32 + fi * 16 + fr;
        a[fi] = *(const f16x8*)&L[row * 64 + (((s * 4 + fc) ^ (fr & 7)) * 8)];
      }
#pragma unroll
      for (int fj = 0; fj < 2; ++fj) {
        int brow = wc_ * 32 + fj * 16 + fr;
        b[fj] = *(const f16x8*)&L[4096 + brow * 64 + (((s * 4 + fc) ^ (fr & 7)) * 8)];
      }
#pragma unroll
      for (int fi = 0; fi < 2; ++fi)
#pragma unroll
        for (int fj = 0; fj < 2; ++fj)
          acc[fi][fj] = __builtin_amdgcn_mfma_f32_16x16x32_f16(a[fi], b[fj], acc[fi][fj], 0, 0, 0);
    }
  };

  stage(0, 0);
  stage(1, 1);
  stage(2, 2);
  int t = 0;
  for (; t < NT - 3; ++t) {
    PHASE_WAIT(8);
    stage(t + 3, (t + 3) & 3);
    compute(t & 3);
  }
  PHASE_WAIT(8);
  compute(t & 3);
  ++t;
  PHASE_WAIT(4);
  compute(t & 3);
  ++t;
  PHASE_WAIT(0);
  compute(t & 3);

#pragma unroll
  for (int fi = 0; fi < 2; ++fi) {
#pragma unroll
    for (int fj = 0; fj < 2; ++fj) {
      int Rb = ybase + wr_ * 32 + fi * 16 + fc * 4;  // wcat row base; gate = j
      int u = Rb >> 2;
      int b = bbase + wc_ * 32 + fj * 16 + fr;
      float p[4];
#pragma unroll
      for (int j = 0; j < 4; ++j) {
        float s = acc[fi][fj][j];
        s += isL1 ? bg1[j * 512 + u] : xw0[b * 2048 + j * 512 + u];
        p[j] = s;
      }
      int ci = b * 512 + u;
      float cprev = c[ci];
      float ig = sig_(p[0]);
      float fg = sig_(p[1]);
      float gg = tanhf(p[2]);
      float og = sig_(p[3]);
      float cn = fg * cprev + ig * gg;
      float hn = og * tanhf(cn);
      c[ci] = cn;
      hout[ci] = f2h(hn);
      if (isL1) ysout[ci] = f2h(hn);
    }
  }
}

// ---------------- final FC: sigmoid(fc1o @ fw2.T + fb2), [2560,13] ----------------
__global__ void fc2_sigmoid(const half_t* __restrict__ in, const float* __restrict__ w,
                            const float* __restrict__ b, float* __restrict__ out) {
  int idx = blockIdx.x * blockDim.x + threadIdx.x;
  if (idx >= 2560 * 13) return;
  int j = idx % 13, r = idx / 13;
  const half_t* ip = in + (size_t)r * 512;
  const float* wp = w + j * 512;
  float s = b[j];
  for (int k = 0; k < 512; k += 8) {
    f16x8 hv = *(const f16x8*)&ip[k];
#pragma unroll
    for (int q = 0; q < 8; ++q) s = fmaf((float)hv[q], wp[k + q], s);
  }
  out[idx] = sig_(s);
}

// ---------------- launch ----------------
extern "C" void kernel_launch(void* const* d_in, const int* in_sizes, int n_in,
                              void* d_out, int out_size, void* d_ws, size_t ws_size,
                              hipStream_t stream) {
  const float* x   = (const float*)d_in[0];
  const float* w1  = (const float*)d_in[1];  const float* b1 = (const float*)d_in[2];
  const float* w2  = (const float*)d_in[3];  const float* b2 = (const float*)d_in[4];
  const float* w3  = (const float*)d_in[5];  const float* b3 = (const float*)d_in[6];
  const float* w4  = (const float*)d_in[7];  const float* b4 = (const float*)d_in[8];
  const float* w5  = (const float*)d_in[9];  const float* b5 = (const float*)d_in[10];
  const float* wih0 = (const float*)d_in[11]; const float* whh0 = (const float*)d_in[12];
  const float* bih0 = (const float*)d_in[13]; const float* bhh0 = (const float*)d_in[14];
  const float* wih1 = (const float*)d_in[15]; const float* whh1 = (const float*)d_in[16];
  const float* bih1 = (const float*)d_in[17]; const float* bhh1 = (const float*)d_in[18];
  const float* fw1 = (const float*)d_in[19]; const float* fb1 = (const float*)d_in[20];
  const float* fw2 = (const float*)d_in[21]; const float* fb2 = (const float*)d_in[22];
  float* out = (float*)d_out;

  // ---- workspace layout (~68.6 MB; 75.6 MB proven safe) ----
  float* bg0 = (float*)d_ws;                // 2048
  float* bg1 = bg0 + 2048;                  // 2048
  float* xw0 = bg1 + 2048;                  // 262144
  float* c0  = xw0 + 262144;                // 65536
  float* c1  = c0 + 65536;                  // 65536
  half_t* h0a = (half_t*)(c1 + 65536);      // 4 x 65536 halves
  half_t* h0b = h0a + 65536;
  half_t* h1a = h0b + 65536;
  half_t* h1b = h1a + 65536;
  half_t* BUF1 = h1b + 65536;               // 8,388,608  [A1 -> A3 -> feat]
  half_t* BUF2 = BUF1 + 8388608;            // 2,768,896  [A2 -> A4 -> ys+fc1o]
  half_t* w1r  = BUF2 + 2768896;            // 26,624
  half_t* w2r  = w1r + 26624;               // 401,408
  half_t* w3r  = w2r + 401408;              // 819,200
  half_t* w4r  = w3r + 819200;              // 3,276,800
  half_t* w5r  = w4r + 3276800;             // 6,553,600
  half_t* wih0h  = w5r + 6553600;           // 1,048,576
  half_t* wcat0h = wih0h + 1048576;         // 1,048,576
  half_t* wcat1h = wcat0h + 1048576;        // 2,097,152
  half_t* fw1h   = wcat1h + 2097152;        // 262,144
  half_t* xpad   = fw1h + 262144;           // union: xpad 5,017,600 h / pbC f32
  float* pbC = (float*)xpad;

  half_t* A1 = BUF1;                        // [131072 px][64]
  half_t* A2 = BUF2;                        // [21632][128]
  half_t* A3 = BUF1;                        // [10368][256]
  half_t* A4 = BUF2;                        // [3200][512]  (A2 dead)
  half_t* feat = BUF1;                      // [128][512]   (A3 dead)
  half_t* ys   = BUF2;                      // [2560][512]  (A4 dead post-conv5)
  half_t* fc1o = BUF2 + 1310720;

  dim3 blk(256);

  // ---- prep: elementwise (1 launch) + LDS-bounce weight transposes (1 launch) ----
  prep_all<<<38152, blk, 0, stream>>>(
      x, w1, wih0, whh0, bih0, bhh0, wih1, whh1, bih1, bhh1, fw1,
      bg0, bg1, c0, (unsigned*)h0a, xpad, w1r, wih0h, fw1h, wcat0h, wcat1h);
  prep_wT<<<1408, blk, 0, stream>>>(w2, w3, w4, w5, w2r, w3r, w4r, w5r);

  // ---- conv stack ----
  conv_mfma<7, 2, 3, 0><<<dim3(2048, 1, 1), blk, 0, stream>>>(
      xpad, w1r, b1, A1, 70, 70, 32, 32, 64, 416, 13, 0.2f, 0);
  conv_mfma128<7, 2, 6, 0><<<dim3(169, 1, 1), blk, 0, stream>>>(
      A1, w2r, b2, A2, 32, 32, 13, 13, 128, 3136, 98, 0.2f, 0);
  conv_mfma128<5, 1, 7, 0><<<dim3(81, 2, 1), blk, 0, stream>>>(
      A2, w3r, b3, A3, 13, 13, 9, 9, 256, 3200, 100, 0.2f, 0);
  conv_mfma128<5, 1, 8, 2><<<dim3(25, 4, 2), blk, 0, stream>>>(
      A3, w4r, b4, pbC, 9, 9, 5, 5, 512, 6400, 100, 0.2f, (long long)3200 * 512);
  finalize_part<<<6400, blk, 0, stream>>>(pbC, b4, A4, 1638400, 2);
  conv_mfma<5, 1, 9, 2><<<dim3(2, 8, 25), blk, 0, stream>>>(
      A4, w5r, b5, pbC, 5, 5, 1, 1, 512, 12800, 16, 0.2f, (long long)65536);
  finalize_part<<<256, blk, 0, stream>>>(pbC, b5, feat, 65536, 25);

  // xw0 = feat @ wih0.T + bg0  [128][2048] f32 (slope=1 -> identity)
  conv_mfma<1, 1, 9, 1><<<dim3(2, 32, 1), blk, 0, stream>>>(
      feat, wih0h, bg0, xw0, 1, 1, 1, 1, 2048, 512, 16, 1.0f, 0);

  // ---- 2-layer LSTM, 20 steps, fused l0(t+1)||l1(t): 21 launches ----
  half_t* h0buf[2] = {h0a, h0b};
  half_t* h1buf[2] = {h1a, h1b};
  lstm_fused<<<dim3(2, 32, 1), blk, 0, stream>>>(
      h0a, h0b, h1a, h1a, wcat0h, wcat1h, xw0, bg1, c0, c1, ys, 1);
  for (int t = 2; t <= 20; ++t) {
    lstm_fused<<<dim3(2, 32, 2), blk, 0, stream>>>(
        h0buf[(t - 1) & 1], h0buf[t & 1], h1buf[t & 1], h1buf[(t - 1) & 1],
        wcat0h, wcat1h, xw0, bg1, c0, c1, ys + (size_t)(t - 2) * 65536, 3);
  }
  lstm_fused<<<dim3(2, 32, 1), blk, 0, stream>>>(
      h0buf[0], h0buf[1], h1buf[1], h1buf[0],
      wcat0h, wcat1h, xw0, bg1, c0, c1, ys + (size_t)19 * 65536, 2);

  // ---- FC head ----
  conv_mfma<1, 1, 9, 0><<<dim3(40, 8, 1), blk, 0, stream>>>(
      ys, fw1h, fb1, fc1o, 1, 1, 1, 1, 512, 512, 16, 0.01f, 0);
  fc2_sigmoid<<<130, blk, 0, stream>>>(fc1o, fw2, fb2, out);
}

// Round 9
// 399.686 us; speedup vs baseline: 1.8135x; 1.0304x over previous
//
#include <hip/hip_runtime.h>
#include <math.h>

typedef _Float16 half_t;
typedef __attribute__((ext_vector_type(8))) _Float16 f16x8;
typedef __attribute__((ext_vector_type(4))) _Float16 f16x4;
typedef __attribute__((ext_vector_type(4))) float f32x4;

#define LEAKY(v, s) ((v) >= 0.f ? (v) : (s) * (v))

__device__ __forceinline__ float sig_(float x) { return 1.f / (1.f + expf(-x)); }
__device__ __forceinline__ half_t f2h(float f) { return (half_t)f; }

#define GLD(gp, lp)                                              \
  __builtin_amdgcn_global_load_lds(                              \
      (const __attribute__((address_space(1))) void*)(gp),       \
      (__attribute__((address_space(3))) void*)(lp), 16, 0, 0)

#define PHASE_WAIT(N)                                            \
  asm volatile("s_waitcnt vmcnt(" #N ")" ::: "memory");          \
  __builtin_amdgcn_s_barrier();                                  \
  __builtin_amdgcn_sched_barrier(0)

// ---------------- merged elementwise prep ----------------
#define QOFF0 2048LL
#define QOFF1 4096LL
#define QOFF2 135168LL
#define QOFF3 266240LL
#define QOFF4 5283840LL
#define QOFF5 5310464LL
#define QOFF6 6359040LL
#define QOFF7 6621184LL
#define QOFF8 7669760LL
#define QOFF9 9766912LL   // total

__global__ void prep_all(
    const float* __restrict__ x, const float* __restrict__ w1,
    const float* __restrict__ wih0, const float* __restrict__ whh0,
    const float* __restrict__ bih0, const float* __restrict__ bhh0,
    const float* __restrict__ wih1, const float* __restrict__ whh1,
    const float* __restrict__ bih1, const float* __restrict__ bhh1,
    const float* __restrict__ fw1,
    float* __restrict__ bg0, float* __restrict__ bg1,
    float* __restrict__ czero, unsigned* __restrict__ hzero,
    half_t* __restrict__ xpad, half_t* __restrict__ w1r,
    half_t* __restrict__ wih0h, half_t* __restrict__ fw1h,
    half_t* __restrict__ wcat0h, half_t* __restrict__ wcat1h) {
  long long i = (long long)blockIdx.x * blockDim.x + threadIdx.x;
  if (i < QOFF0) {
    bg0[i] = bih0[i] + bhh0[i];
  } else if (i < QOFF1) {
    long long j = i - QOFF0;
    bg1[j] = bih1[j] + bhh1[j];
  } else if (i < QOFF2) {
    czero[i - QOFF1] = 0.f;
  } else if (i < QOFF3) {
    hzero[i - QOFF2] = 0u;
  } else if (i < QOFF4) {
    long long j = i - QOFF3;
    int c = j & 7;
    long long t = j >> 3;
    int iw = t % 70; t /= 70;
    int ih = t % 70;
    int n = t / 70;
    float v = 0.f;
    if (c < 3 && ih >= 3 && ih < 67 && iw >= 3 && iw < 67)
      v = x[((n * 3 + c) * 64 + (ih - 3)) * 64 + (iw - 3)];
    xpad[j] = f2h(v);
  } else if (i < QOFF5) {
    int j = (int)(i - QOFF4);
    int kg = j % 416, co = j / 416;
    int ci = kg & 7, tap = kg >> 3;
    float v = 0.f;
    if (tap < 49 && ci < 3) {
      int kh = tap / 7, kw = tap % 7;
      v = w1[((co * 3 + ci) * 7 + kh) * 7 + kw];
    }
    w1r[j] = f2h(v);
  } else if (i < QOFF6) {
    int j = (int)(i - QOFF5);
    wih0h[j] = f2h(wih0[j]);
  } else if (i < QOFF7) {
    int j = (int)(i - QOFF6);
    fw1h[j] = f2h(fw1[j]);
  } else if (i < QOFF8) {
    int j = (int)(i - QOFF7);
    int r = j >> 9, k = j & 511;
    int u = r >> 2, g = r & 3;
    wcat0h[j] = f2h(whh0[(g * 512 + u) * 512 + k]);
  } else if (i < QOFF9) {
    int j = (int)(i - QOFF8);
    int r = j >> 10, k = j & 1023;
    int u = r >> 2, g = r & 3;
    int row = g * 512 + u;
    wcat1h[j] = f2h(k < 512 ? wih1[row * 512 + k] : whh1[row * 512 + (k - 512)]);
  }
}

// ---------------- LDS-bounce weight transpose ----------------
__global__ __launch_bounds__(256) void prep_wT(
    const float* __restrict__ w2, const float* __restrict__ w3,
    const float* __restrict__ w4, const float* __restrict__ w5,
    half_t* __restrict__ w2r, half_t* __restrict__ w3r,
    half_t* __restrict__ w4r, half_t* __restrict__ w5r) {
  __shared__ float T[12800];
  int bid = blockIdx.x, tid = threadIdx.x;
  const float* W;
  half_t* D;
  int co, Cin, TAP, lg2;
  if (bid < 128) {
    W = w2; D = w2r; co = bid; Cin = 64; TAP = 49; lg2 = 6;
  } else if (bid < 384) {
    W = w3; D = w3r; co = bid - 128; Cin = 128; TAP = 25; lg2 = 7;
  } else if (bid < 896) {
    W = w4; D = w4r; co = bid - 384; Cin = 256; TAP = 25; lg2 = 8;
  } else {
    W = w5; D = w5r; co = bid - 896; Cin = 512; TAP = 25; lg2 = 9;
  }
  int n = Cin * TAP;
  const float* src = W + (size_t)co * n;
  for (int i = tid; i < n; i += 256) T[i] = src[i];
  __syncthreads();
  half_t* dst = D + (size_t)co * n;
  for (int j = tid; j < n; j += 256) {
    int ci = j & (Cin - 1);
    int tap = j >> lg2;
    dst[j] = f2h(T[ci * TAP + tap]);
  }
}

// ---------------- 64x64 fp16 MFMA conv / GEMM ----------------
template <int KW, int S, int LOG2CIN, int OUTMODE>
__global__ __launch_bounds__(256) void conv_mfma(
    const half_t* __restrict__ xin, const half_t* __restrict__ wr,
    const float* __restrict__ bias, void* __restrict__ outp,
    int Hin, int Win, int Hout, int Wout, int Cout, int K, int ktiles, float slope,
    long long zstride) {
  constexpr int CIN = 1 << LOG2CIN;
  __shared__ half_t lds[4][4096];
  const int tid = threadIdx.x;
  const int lane = tid & 63, wid = tid >> 6;
  const int sRow = tid >> 2, sCh = tid & 3;
  const int sSwz = sCh ^ ((sRow ^ (sRow >> 2)) & 3);
  const int kt0 = blockIdx.z * ktiles;
  const half_t* gArow = wr + (size_t)(blockIdx.y * 64 + sRow) * K + sSwz * 8;
  int p = blockIdx.x * 64 + sRow;
  int hw = Hout * Wout;
  int n = p / hw;
  int rem = p - n * hw;
  int oh = rem / Wout;
  int ow = rem - oh * Wout;
  const half_t* xb = xin + ((size_t)(n * Hin + oh * S) * Win + ow * S) * CIN;
  const int fr = lane & 15, fc = lane >> 4;
  const int r0 = (wid & 1) * 32, c0 = (wid >> 1) * 32;
  const int sw = (fc ^ ((fr ^ (fr >> 2)) & 3)) * 8;
  const int ia0 = (r0 + fr) * 32 + sw;
  const int ia1 = (r0 + 16 + fr) * 32 + sw;
  const int ib0 = 2048 + (c0 + fr) * 32 + sw;
  const int ib1 = 2048 + (c0 + 16 + fr) * 32 + sw;

  auto stage = [&](int t, int buf) {
    GLD(gArow + (size_t)(kt0 + t) * 32, &lds[buf][wid * 512]);
    int kg = (kt0 + t) * 32 + sSwz * 8;
    int ci = kg & (CIN - 1);
    int tap = kg >> LOG2CIN;
    int kh = tap / KW, kw = tap - kh * KW;
    GLD(xb + (kh * Win + kw) * CIN + ci, &lds[buf][2048 + wid * 512]);
  };

  f32x4 acc00 = {0.f, 0.f, 0.f, 0.f};
  f32x4 acc01 = acc00, acc10 = acc00, acc11 = acc00;

  auto compute = [&](int buf) {
    const half_t* L = &lds[buf][0];
    f16x8 a0 = *(const f16x8*)&L[ia0];
    f16x8 a1 = *(const f16x8*)&L[ia1];
    f16x8 b0 = *(const f16x8*)&L[ib0];
    f16x8 b1 = *(const f16x8*)&L[ib1];
    acc00 = __builtin_amdgcn_mfma_f32_16x16x32_f16(a0, b0, acc00, 0, 0, 0);
    acc01 = __builtin_amdgcn_mfma_f32_16x16x32_f16(a0, b1, acc01, 0, 0, 0);
    acc10 = __builtin_amdgcn_mfma_f32_16x16x32_f16(a1, b0, acc10, 0, 0, 0);
    acc11 = __builtin_amdgcn_mfma_f32_16x16x32_f16(a1, b1, acc11, 0, 0, 0);
  };

  stage(0, 0);
  stage(1, 1);
  stage(2, 2);
  int t = 0;
  for (; t < ktiles - 3; ++t) {
    PHASE_WAIT(4);
    stage(t + 3, (t + 3) & 3);
    compute(t & 3);
  }
  PHASE_WAIT(4);
  compute(t & 3);
  ++t;
  PHASE_WAIT(2);
  compute(t & 3);
  ++t;
  PHASE_WAIT(0);
  compute(t & 3);

#pragma unroll
  for (int am = 0; am < 2; ++am) {
#pragma unroll
    for (int bn = 0; bn < 2; ++bn) {
      f32x4 a = am == 0 ? (bn == 0 ? acc00 : acc01) : (bn == 0 ? acc10 : acc11);
      int co = blockIdx.y * 64 + r0 + am * 16 + fc * 4;
      int px = blockIdx.x * 64 + c0 + bn * 16 + fr;
      size_t o = (size_t)px * Cout + co;
      if (OUTMODE == 2) {
        float* pb = (float*)outp + (size_t)blockIdx.z * zstride;
        *(f32x4*)&pb[o] = a;
      } else {
        f32x4 bb = *(const f32x4*)&bias[co];
        f32x4 v;
#pragma unroll
        for (int j = 0; j < 4; ++j) {
          float tt = a[j] + bb[j];
          v[j] = LEAKY(tt, slope);
        }
        if (OUTMODE == 1) {
          *(f32x4*)&((float*)outp)[o] = v;
        } else {
          f16x4 hv;
#pragma unroll
          for (int j = 0; j < 4; ++j) hv[j] = f2h(v[j]);
          *(f16x4*)&((half_t*)outp)[o] = hv;
        }
      }
    }
  }
}

// ---------------- 128x128 fp16 MFMA conv, XCD-swizzled 1D grid ----------------
// Launch 1D grid of X*G blocks; decode g = L % G (panel group = y + Y*z),
// bx = L / G. Block L lands on XCD L%8, so all x-blocks of a panel share an
// XCD when G | 8 or 8 | G -> weight panel stays L2-resident (T1).
// OUTMODE: 0 fp16+bias+leaky; 3 fp16 raw partial at bz*zstride.
template <int KW, int S, int LOG2CIN, int OUTMODE>
__global__ __launch_bounds__(256) void conv_mfma128(
    const half_t* __restrict__ xin, const half_t* __restrict__ wr,
    const float* __restrict__ bias, void* __restrict__ outp,
    int Hin, int Win, int Hout, int Wout, int Cout, int K, int ktiles, float slope,
    long long zstride, int Y, int G) {
  constexpr int CIN = 1 << LOG2CIN;
  __shared__ half_t lds[4][8192];
  const int L = blockIdx.x;
  const int bx = L / G;
  const int g = L % G;
  const int by = g % Y;
  const int bz = g / Y;
  const int tid = threadIdx.x;
  const int lane = tid & 63, wid = tid >> 6;
  const int sRow = tid >> 2, sCh = tid & 3;
  const int sSwz = sCh ^ ((sRow ^ (sRow >> 2)) & 3);
  const int kt0 = bz * ktiles;
  const half_t* gA0 = wr + (size_t)(by * 128 + sRow) * K + sSwz * 8;
  const half_t* gA1 = wr + (size_t)(by * 128 + 64 + sRow) * K + sSwz * 8;
  int hw = Hout * Wout;
  int p0 = bx * 128 + sRow;
  int n0 = p0 / hw, r0p = p0 - n0 * hw, oh0 = r0p / Wout, ow0 = r0p - oh0 * Wout;
  const half_t* xb0 = xin + ((size_t)(n0 * Hin + oh0 * S) * Win + ow0 * S) * CIN;
  int p1 = p0 + 64;
  int n1 = p1 / hw, r1p = p1 - n1 * hw, oh1 = r1p / Wout, ow1 = r1p - oh1 * Wout;
  const half_t* xb1 = xin + ((size_t)(n1 * Hin + oh1 * S) * Win + ow1 * S) * CIN;

  const int fr = lane & 15, fc = lane >> 4;
  const int wr_ = wid & 1, wc_ = wid >> 1;
  const int sw = (fc ^ ((fr ^ (fr >> 2)) & 3)) * 8;
  const int iaB = (wr_ * 64 + fr) * 32 + sw;
  const int ibB = 4096 + (wc_ * 64 + fr) * 32 + sw;

  auto stage = [&](int t, int buf) {
    half_t* LB = &lds[buf][0];
    GLD(gA0 + (size_t)(kt0 + t) * 32, LB + wid * 512);
    GLD(gA1 + (size_t)(kt0 + t) * 32, LB + 2048 + wid * 512);
    int kg = (kt0 + t) * 32 + sSwz * 8;
    int ci = kg & (CIN - 1);
    int tap = kg >> LOG2CIN;
    int kh = tap / KW, kw = tap - kh * KW;
    int xoff = (kh * Win + kw) * CIN + ci;
    GLD(xb0 + xoff, LB + 4096 + wid * 512);
    GLD(xb1 + xoff, LB + 6144 + wid * 512);
  };

  f32x4 acc[4][4];
#pragma unroll
  for (int i = 0; i < 4; ++i)
#pragma unroll
    for (int j = 0; j < 4; ++j) acc[i][j] = (f32x4){0.f, 0.f, 0.f, 0.f};

  auto compute = [&](int buf) {
    const half_t* L2 = &lds[buf][0];
    f16x8 a[4], b[4];
#pragma unroll
    for (int fi = 0; fi < 4; ++fi) a[fi] = *(const f16x8*)&L2[iaB + fi * 512];
#pragma unroll
    for (int fj = 0; fj < 4; ++fj) b[fj] = *(const f16x8*)&L2[ibB + fj * 512];
#pragma unroll
    for (int fi = 0; fi < 4; ++fi)
#pragma unroll
      for (int fj = 0; fj < 4; ++fj)
        acc[fi][fj] = __builtin_amdgcn_mfma_f32_16x16x32_f16(a[fi], b[fj], acc[fi][fj], 0, 0, 0);
  };

  stage(0, 0);
  stage(1, 1);
  stage(2, 2);
  int t = 0;
  for (; t < ktiles - 3; ++t) {
    PHASE_WAIT(8);
    stage(t + 3, (t + 3) & 3);
    compute(t & 3);
  }
  PHASE_WAIT(8);
  compute(t & 3);
  ++t;
  PHASE_WAIT(4);
  compute(t & 3);
  ++t;
  PHASE_WAIT(0);
  compute(t & 3);

#pragma unroll
  for (int fi = 0; fi < 4; ++fi) {
#pragma unroll
    for (int fj = 0; fj < 4; ++fj) {
      int co = by * 128 + wr_ * 64 + fi * 16 + fc * 4;
      int px = bx * 128 + wc_ * 64 + fj * 16 + fr;
      size_t o = (size_t)px * Cout + co;
      if (OUTMODE == 3) {
        half_t* pb = (half_t*)outp + (size_t)bz * zstride;
        f16x4 hv;
#pragma unroll
        for (int j = 0; j < 4; ++j) hv[j] = f2h(acc[fi][fj][j]);
        *(f16x4*)&pb[o] = hv;
      } else {
        f32x4 bb = *(const f32x4*)&bias[co];
        f16x4 hv;
#pragma unroll
        for (int j = 0; j < 4; ++j) {
          float tt = acc[fi][fj][j] + bb[j];
          hv[j] = f2h(LEAKY(tt, slope));
        }
        *(f16x4*)&((half_t*)outp)[o] = hv;
      }
    }
  }
}

// reduce K-split f32 partials (conv5)
__global__ void finalize_part(const float* __restrict__ pb, const float* __restrict__ bias,
                              half_t* __restrict__ out, int size, int nz) {
  int i = blockIdx.x * blockDim.x + threadIdx.x;
  if (i >= size) return;
  float s = bias[i & 511];
  for (int z = 0; z < nz; ++z) s += pb[(size_t)z * size + i];
  out[i] = f2h(LEAKY(s, 0.2f));
}

// reduce fp16 K-split partials, vectorized x8: out = leaky(sum_z pb + bias, 0.2)
__global__ void finalize_h(const half_t* __restrict__ pb, const float* __restrict__ bias,
                           half_t* __restrict__ out, int size8, int nz, int cmask,
                           long long zstride) {
  int idx = blockIdx.x * blockDim.x + threadIdx.x;
  if (idx >= size8) return;
  long long i = (long long)idx * 8;
  float s[8];
#pragma unroll
  for (int q = 0; q < 8; ++q) s[q] = bias[(int)((i + q) & cmask)];
  for (int z = 0; z < nz; ++z) {
    f16x8 v = *(const f16x8*)&pb[(size_t)z * zstride + i];
#pragma unroll
    for (int q = 0; q < 8; ++q) s[q] += (float)v[q];
  }
  f16x8 o;
#pragma unroll
  for (int q = 0; q < 8; ++q) o[q] = f2h(LEAKY(s[q], 0.2f));
  *(f16x8*)&out[i] = o;
}

// ---------------- fused LSTM step, BK=64 (round-8 proven) ----------------
__global__ __launch_bounds__(256) void lstm_fused(
    const half_t* __restrict__ h0in, half_t* __restrict__ h0out,
    const half_t* __restrict__ h1in, half_t* __restrict__ h1out,
    const half_t* __restrict__ wcat0, const half_t* __restrict__ wcat1,
    const float* __restrict__ xw0, const float* __restrict__ bg1,
    float* __restrict__ c0, float* __restrict__ c1,
    half_t* __restrict__ ysout, int roles) {
  const bool isL1 = (roles == 2) || (blockIdx.z == 1);
  const int NT = isL1 ? 16 : 8;
  const half_t* wcat = isL1 ? wcat1 : wcat0;
  float* c = isL1 ? c1 : c0;
  half_t* hout = isL1 ? h1out : h0out;
  const int K = NT * 64;

  __shared__ half_t lds[4][8192];
  const int tid = threadIdx.x;
  const int lane = tid & 63, wid = tid >> 6;
  const int ybase = blockIdx.y * 64, bbase = blockIdx.x * 64;
  const int rA0 = wid * 16 + (lane >> 3);
  const int rA1 = rA0 + 8;
  const int chS = ((lane & 7) ^ ((lane >> 3) & 7)) * 8;
  const half_t* gA0 = wcat + (size_t)(ybase + rA0) * K + chS;
  const half_t* gA1 = wcat + (size_t)(ybase + rA1) * K + chS;
  const size_t hb0 = (size_t)(bbase + rA0) * 512 + chS;
  const size_t hb1 = (size_t)(bbase + rA1) * 512 + chS;

  auto stage = [&](int t, int buf) {
    GLD(gA0 + t * 64, &lds[buf][wid * 1024]);
    GLD(gA1 + t * 64, &lds[buf][wid * 1024 + 512]);
    const half_t* hs = (isL1 && t >= 8) ? h1in : h0in;
    int koff = (isL1 && t >= 8) ? (t - 8) * 64 : t * 64;
    GLD(hs + hb0 + koff, &lds[buf][4096 + wid * 1024]);
    GLD(hs + hb1 + koff, &lds[buf][4096 + wid * 1024 + 512]);
  };

  const int fr = lane & 15, fc = lane >> 4;
  const int wr_ = wid & 1, wc_ = wid >> 1;

  f32x4 acc[2][2];
#pragma unroll
  for (int fi = 0; fi < 2; ++fi)
#pragma unroll
    for (int fj = 0; fj < 2; ++fj) acc[fi][fj] = (f32x4){0.f, 0.f, 0.f, 0.f};

  auto compute = [&](int buf) {
    const half_t* L = &lds[buf][0];
#pragma unroll
    for (int s = 0; s < 2; ++s) {
      f16x8 a[2], b[2];
#pragma unroll
      for (int fi = 0; fi < 2; ++fi) {
        int row = wr_ * 32 + fi * 16 + fr;
        a[fi] = *(const f16x8*)&L[row * 64 + (((s * 4 + fc) ^ (fr & 7)) * 8)];
      }
#pragma unroll
      for (int fj = 0; fj < 2; ++fj) {
        int brow = wc_ * 32 + fj * 16 + fr;
        b[fj] = *(const f16x8*)&L[4096 + brow * 64 + (((s * 4 + fc) ^ (fr & 7)) * 8)];
      }
#pragma unroll
      for (int fi = 0; fi < 2; ++fi)
#pragma unroll
        for (int fj = 0; fj < 2; ++fj)
          acc[fi][fj] = __builtin_amdgcn_mfma_f32_16x16x32_f16(a[fi], b[fj], acc[fi][fj], 0, 0, 0);
    }
  };

  stage(0, 0);
  stage(1, 1);
  stage(2, 2);
  int t = 0;
  for (; t < NT - 3; ++t) {
    PHASE_WAIT(8);
    stage(t + 3, (t + 3) & 3);
    compute(t & 3);
  }
  PHASE_WAIT(8);
  compute(t & 3);
  ++t;
  PHASE_WAIT(4);
  compute(t & 3);
  ++t;
  PHASE_WAIT(0);
  compute(t & 3);

#pragma unroll
  for (int fi = 0; fi < 2; ++fi) {
#pragma unroll
    for (int fj = 0; fj < 2; ++fj) {
      int Rb = ybase + wr_ * 32 + fi * 16 + fc * 4;
      int u = Rb >> 2;
      int b = bbase + wc_ * 32 + fj * 16 + fr;
      float p[4];
#pragma unroll
      for (int j = 0; j < 4; ++j) {
        float s = acc[fi][fj][j];
        s += isL1 ? bg1[j * 512 + u] : xw0[b * 2048 + j * 512 + u];
        p[j] = s;
      }
      int ci = b * 512 + u;
      float cprev = c[ci];
      float ig = sig_(p[0]);
      float fg = sig_(p[1]);
      float gg = tanhf(p[2]);
      float og = sig_(p[3]);
      float cn = fg * cprev + ig * gg;
      float hn = og * tanhf(cn);
      c[ci] = cn;
      hout[ci] = f2h(hn);
      if (isL1) ysout[ci] = f2h(hn);
    }
  }
}

// ---------------- final FC: sigmoid(fc1o @ fw2.T + fb2), [2560,13] ----------------
__global__ void fc2_sigmoid(const half_t* __restrict__ in, const float* __restrict__ w,
                            const float* __restrict__ b, float* __restrict__ out) {
  int idx = blockIdx.x * blockDim.x + threadIdx.x;
  if (idx >= 2560 * 13) return;
  int j = idx % 13, r = idx / 13;
  const half_t* ip = in + (size_t)r * 512;
  const float* wp = w + j * 512;
  float s = b[j];
  for (int k = 0; k < 512; k += 8) {
    f16x8 hv = *(const f16x8*)&ip[k];
#pragma unroll
    for (int q = 0; q < 8; ++q) s = fmaf((float)hv[q], wp[k + q], s);
  }
  out[idx] = sig_(s);
}

// ---------------- launch ----------------
extern "C" void kernel_launch(void* const* d_in, const int* in_sizes, int n_in,
                              void* d_out, int out_size, void* d_ws, size_t ws_size,
                              hipStream_t stream) {
  const float* x   = (const float*)d_in[0];
  const float* w1  = (const float*)d_in[1];  const float* b1 = (const float*)d_in[2];
  const float* w2  = (const float*)d_in[3];  const float* b2 = (const float*)d_in[4];
  const float* w3  = (const float*)d_in[5];  const float* b3 = (const float*)d_in[6];
  const float* w4  = (const float*)d_in[7];  const float* b4 = (const float*)d_in[8];
  const float* w5  = (const float*)d_in[9];  const float* b5 = (const float*)d_in[10];
  const float* wih0 = (const float*)d_in[11]; const float* whh0 = (const float*)d_in[12];
  const float* bih0 = (const float*)d_in[13]; const float* bhh0 = (const float*)d_in[14];
  const float* wih1 = (const float*)d_in[15]; const float* whh1 = (const float*)d_in[16];
  const float* bih1 = (const float*)d_in[17]; const float* bhh1 = (const float*)d_in[18];
  const float* fw1 = (const float*)d_in[19]; const float* fb1 = (const float*)d_in[20];
  const float* fw2 = (const float*)d_in[21]; const float* fb2 = (const float*)d_in[22];
  float* out = (float*)d_out;

  // ---- workspace layout (within 75.6 MB proven) ----
  float* bg0 = (float*)d_ws;                // 2048
  float* bg1 = bg0 + 2048;                  // 2048
  float* xw0 = bg1 + 2048;                  // 262144
  float* c0  = xw0 + 262144;                // 65536
  float* c1  = c0 + 65536;                  // 65536
  half_t* h0a = (half_t*)(c1 + 65536);      // 4 x 65536 halves
  half_t* h0b = h0a + 65536;
  half_t* h1a = h0b + 65536;
  half_t* h1b = h1a + 65536;
  half_t* BUF1 = h1b + 65536;               // 8,388,608  [A1 -> A3 -> feat]
  half_t* BUF2 = BUF1 + 8388608;            // 2,768,896  [A2 -> A4 -> ys+fc1o]
  half_t* w1r  = BUF2 + 2768896;            // 26,624
  half_t* w2r  = w1r + 26624;               // 401,408
  half_t* w3r  = w2r + 401408;              // 819,200
  half_t* w4r  = w3r + 819200;              // 3,276,800
  half_t* w5r  = w4r + 3276800;             // 6,553,600
  half_t* wih0h  = w5r + 6553600;           // 1,048,576
  half_t* wcat0h = wih0h + 1048576;         // 1,048,576
  half_t* wcat1h = wcat0h + 1048576;        // 2,097,152
  half_t* fw1h   = wcat1h + 2097152;        // 262,144
  half_t* xpad   = fw1h + 262144;           // union region (<=20 MB to proven cap):
  half_t* pbH = xpad;                       //   fp16 partials (<=6,553,600 halves)
  float* pbC = (float*)xpad;                //   f32 partials (conv5, 1,638,400)

  half_t* A1 = BUF1;                        // [131072 px][64]
  half_t* A2 = BUF2;                        // [21632][128]
  half_t* A3 = BUF1;                        // [10368][256]
  half_t* A4 = BUF2;                        // [3200][512]  (A2 dead)
  half_t* feat = BUF1;                      // [128][512]   (A3 dead)
  half_t* ys   = BUF2;                      // [2560][512]  (A4 dead post-conv5)
  half_t* fc1o = BUF2 + 1310720;

  dim3 blk(256);

  // ---- prep ----
  prep_all<<<38152, blk, 0, stream>>>(
      x, w1, wih0, whh0, bih0, bhh0, wih1, whh1, bih1, bhh1, fw1,
      bg0, bg1, c0, (unsigned*)h0a, xpad, w1r, wih0h, fw1h, wcat0h, wcat1h);
  prep_wT<<<1408, blk, 0, stream>>>(w2, w3, w4, w5, w2r, w3r, w4r, w5r);

  // ---- conv stack ----
  // conv1: 64x64 tile (2048 blocks)
  conv_mfma<7, 2, 3, 0><<<dim3(2048, 1, 1), blk, 0, stream>>>(
      xpad, w1r, b1, A1, 70, 70, 32, 32, 64, 416, 13, 0.2f, 0);
  // conv2: 128x128, z=2 K-split, fp16 partials, XCD-swizzled (G=2)
  conv_mfma128<7, 2, 6, 3><<<338, blk, 0, stream>>>(
      A1, w2r, b2, pbH, 32, 32, 13, 13, 128, 3136, 49, 0.2f, 2768896LL, 1, 2);
  finalize_h<<<1352, blk, 0, stream>>>(pbH, b2, A2, 346112, 2, 127, 2768896LL);
  // conv3: z=2, G=4
  conv_mfma128<5, 1, 7, 3><<<324, blk, 0, stream>>>(
      A2, w3r, b3, pbH, 13, 13, 9, 9, 256, 3200, 50, 0.2f, 2654208LL, 2, 4);
  finalize_h<<<1296, blk, 0, stream>>>(pbH, b3, A3, 331776, 2, 255, 2654208LL);
  // conv4: z=4, G=16
  conv_mfma128<5, 1, 8, 3><<<400, blk, 0, stream>>>(
      A3, w4r, b4, pbH, 9, 9, 5, 5, 512, 6400, 50, 0.2f, 1638400LL, 4, 16);
  finalize_h<<<800, blk, 0, stream>>>(pbH, b4, A4, 204800, 4, 511, 1638400LL);
  // conv5: 64x64, z=25 f32 partials
  conv_mfma<5, 1, 9, 2><<<dim3(2, 8, 25), blk, 0, stream>>>(
      A4, w5r, b5, pbC, 5, 5, 1, 1, 512, 12800, 16, 0.2f, (long long)65536);
  finalize_part<<<256, blk, 0, stream>>>(pbC, b5, feat, 65536, 25);

  // xw0 = feat @ wih0.T + bg0  [128][2048] f32 (slope=1 -> identity)
  conv_mfma<1, 1, 9, 1><<<dim3(2, 32, 1), blk, 0, stream>>>(
      feat, wih0h, bg0, xw0, 1, 1, 1, 1, 2048, 512, 16, 1.0f, 0);

  // ---- 2-layer LSTM, 20 steps, fused l0(t+1)||l1(t): 21 launches ----
  half_t* h0buf[2] = {h0a, h0b};
  half_t* h1buf[2] = {h1a, h1b};
  lstm_fused<<<dim3(2, 32, 1), blk, 0, stream>>>(
      h0a, h0b, h1a, h1a, wcat0h, wcat1h, xw0, bg1, c0, c1, ys, 1);
  for (int t = 2; t <= 20; ++t) {
    lstm_fused<<<dim3(2, 32, 2), blk, 0, stream>>>(
        h0buf[(t - 1) & 1], h0buf[t & 1], h1buf[t & 1], h1buf[(t - 1) & 1],
        wcat0h, wcat1h, xw0, bg1, c0, c1, ys + (size_t)(t - 2) * 65536, 3);
  }
  lstm_fused<<<dim3(2, 32, 1), blk, 0, stream>>>(
      h0buf[0], h0buf[1], h1buf[1], h1buf[0],
      wcat0h, wcat1h, xw0, bg1, c0, c1, ys + (size_t)19 * 65536, 2);

  // ---- FC head ----
  conv_mfma<1, 1, 9, 0><<<dim3(40, 8, 1), blk, 0, stream>>>(
      ys, fw1h, fb1, fc1o, 1, 1, 1, 1, 512, 512, 16, 0.01f, 0);
  fc2_sigmoid<<<130, blk, 0, stream>>>(fc1o, fw2, fb2, out);
}